// Round 8
// baseline (552.918 us; speedup 1.0000x reference)
//
#include <hip/hip_runtime.h>
#include <cstdint>
#include <cstddef>

// Problem constants (match reference)
#define B_  4
#define S_  2048
#define D_  256
#define H_  8
#define FD_ 512              // F*D
#define N_  (B_*S_)          // 8192 rows
#define HD_ (H_*D_)          // 2048 concat dim
#define EPS 1e-5f

typedef __attribute__((ext_vector_type(8))) short bf16x8;   // 8 bf16 in 4 VGPRs
typedef __attribute__((ext_vector_type(8))) unsigned short u16x8;
typedef __attribute__((ext_vector_type(4))) float f32x4;

__device__ __forceinline__ unsigned short f2bf(float f) {
  union { float f; unsigned u; } x; x.f = f;
  unsigned u = x.u;
  return (unsigned short)((u + 0x7FFFu + ((u >> 16) & 1u)) >> 16);  // RNE
}
__device__ __forceinline__ float bf2f(unsigned short h) {
  union { unsigned u; float f; } x; x.u = ((unsigned)h) << 16; return x.f;
}

// Coalesced async global->LDS, 16 B/lane; LDS dest = wave-uniform base +
// lane*16 (m104/m108); gptr is per-lane (lets us permute the source).
__device__ __forceinline__ void glds16(const void* gptr, void* ldsptr) {
  __builtin_amdgcn_global_load_lds(
      (__attribute__((address_space(1))) void*)gptr,
      (__attribute__((address_space(3))) void*)ldsptr,
      16, 0, 0);
}

// XOR-swizzled LDS tile addressing (in shorts; unit = 16 B).
// Row r, unit u stored at (u&~7)|((u&7)^(r&7)) -> conflict-free b128 phases.
__device__ __forceinline__ int sw32(int row, int u) {      // 32 units/row (512 B)
  return (row*32 + ((u & 24) | ((u & 7) ^ (row & 7)))) * 8;
}
__device__ __forceinline__ int sw16(int row, int u) {      // 16 units/row (256 B)
  return (row*16 + ((u & 8) | ((u & 7) ^ (row & 7)))) * 8;
}

// ---------------------------------------------------------------------------
// Prep 1: cast X fp32 -> bf16. grid 1024, block 256.
// ---------------------------------------------------------------------------
__global__ __launch_bounds__(256) void cast_x_kernel(
    const float* __restrict__ X, unsigned short* __restrict__ Xb)
{
  const size_t i8 = ((size_t)blockIdx.x * 256 + threadIdx.x) * 8;
  float4 a = *(const float4*)&X[i8];
  float4 b = *(const float4*)&X[i8 + 4];
  u16x8 o;
  o[0]=f2bf(a.x); o[1]=f2bf(a.y); o[2]=f2bf(a.z); o[3]=f2bf(a.w);
  o[4]=f2bf(b.x); o[5]=f2bf(b.y); o[6]=f2bf(b.z); o[7]=f2bf(b.w);
  *(u16x8*)&Xb[i8] = o;
}

// ---------------------------------------------------------------------------
// Prep 2: Wq/Wk/Wv [h][d][e] fp32 -> Wt bf16 [w][e][d] (transposed), scale
// 0.25 folded into q,k. grid (4,4,24), block 256.
// ---------------------------------------------------------------------------
__global__ __launch_bounds__(256) void prep_w_kernel(
    const float* __restrict__ Wq, const float* __restrict__ Wk,
    const float* __restrict__ Wv, unsigned short* __restrict__ Wt)
{
  __shared__ float tile[64][65];
  const int tid = threadIdx.x;
  const int d0 = blockIdx.x * 64, e0 = blockIdx.y * 64;
  const int w = blockIdx.z;
  const float* src;
  float scale;
  if (w < 8)       { src = Wq + (size_t)w*D_*D_;      scale = 0.25f; }
  else if (w < 16) { src = Wk + (size_t)(w-8)*D_*D_;  scale = 0.25f; }
  else             { src = Wv + (size_t)(w-16)*D_*D_; scale = 1.0f;  }
  {
    int r = tid >> 2, c16 = (tid & 3) * 16;
    const float* s = src + (size_t)(d0 + r)*D_ + e0 + c16;
    #pragma unroll
    for (int u = 0; u < 4; ++u) *(float4*)&tile[r][c16 + u*4] = *(const float4*)(s + u*4);
  }
  __syncthreads();
  {
    int er = tid >> 2, dc = (tid & 3) * 16;
    u16x8 o0, o1;
    #pragma unroll
    for (int j = 0; j < 8; ++j) {
      o0[j] = f2bf(tile[dc + j][er] * scale);
      o1[j] = f2bf(tile[dc + 8 + j][er] * scale);
    }
    unsigned short* dst = Wt + ((size_t)w*D_ + e0 + er)*D_ + d0 + dc;
    *(u16x8*)(dst)     = o0;
    *(u16x8*)(dst + 8) = o1;
  }
}

// ---------------------------------------------------------------------------
// Prep 3 (generic): transpose-cast src fp32 [R][C] -> dst bf16 [C][R].
// grid (R/64, C/64), block 256. Used for Wz, W1, W2.
// ---------------------------------------------------------------------------
__global__ __launch_bounds__(256) void tcast_kernel(
    const float* __restrict__ src, unsigned short* __restrict__ dst,
    int R, int C)
{
  __shared__ float tile[64][65];
  const int tid = threadIdx.x;
  const int r0 = blockIdx.x * 64, c0 = blockIdx.y * 64;
  {
    int r = tid >> 2, c16 = (tid & 3) * 16;
    const float* s = src + (size_t)(r0 + r)*C + c0 + c16;
    #pragma unroll
    for (int u = 0; u < 4; ++u) *(float4*)&tile[r][c16 + u*4] = *(const float4*)(s + u*4);
  }
  __syncthreads();
  {
    int cr = tid >> 2, rc = (tid & 3) * 16;
    u16x8 o0, o1;
    #pragma unroll
    for (int j = 0; j < 8; ++j) {
      o0[j] = f2bf(tile[rc + j][cr]);
      o1[j] = f2bf(tile[rc + 8 + j][cr]);
    }
    unsigned short* d = dst + (size_t)(c0 + cr)*R + r0 + rc;
    *(u16x8*)(d)     = o0;
    *(u16x8*)(d + 8) = o1;
  }
}

// ---------------------------------------------------------------------------
// Kernel A: QKV projections, MFMA bf16, swizzled LDS. 24 GEMMs M=8192 N=256
// K=256. grid (128, 4, 24), block 256. (unchanged)
// ---------------------------------------------------------------------------
__global__ __launch_bounds__(256) void qkv_kernel(
    const unsigned short* __restrict__ Xb, const unsigned short* __restrict__ Wt,
    unsigned short* __restrict__ q, unsigned short* __restrict__ k,
    unsigned short* __restrict__ v)
{
  __shared__ unsigned short Xt[64*32*8];     // 32 KB
  __shared__ unsigned short Wtile[64*32*8];  // 32 KB
  const int tid = threadIdx.x;
  const int w4 = tid >> 6, lane = tid & 63;
  const int c = lane & 15, qd = lane >> 4;
  const int n0 = blockIdx.x * 64;
  const int e0 = blockIdx.y * 64;
  const int w  = blockIdx.z;

  unsigned short* obase;
  if (w < 8)       obase = q + (size_t)w*N_*D_;
  else if (w < 16) obase = k + (size_t)(w-8)*N_*D_;
  else             obase = v + (size_t)(w-16)*N_*D_;

  {
    const char* xg = (const char*)Xb + (size_t)n0*512;
    const char* wg = (const char*)Wt + ((size_t)w*D_ + e0)*512;
    #pragma unroll
    for (int i = 0; i < 8; ++i) {
      int g = w4*8 + i;
      int r = 2*g + (lane >> 5);
      int su = lane & 31;
      int u = (su & 24) | ((su & 7) ^ (r & 7));
      glds16(xg + (size_t)r*512 + u*16, &Xt[g*512]);
      glds16(wg + (size_t)r*512 + u*16, &Wtile[g*512]);
    }
  }
  __syncthreads();

  f32x4 sc[4];
  #pragma unroll
  for (int nc = 0; nc < 4; ++nc) sc[nc] = (f32x4){0.f,0.f,0.f,0.f};
  #pragma unroll
  for (int ks = 0; ks < 8; ++ks) {
    bf16x8 xa = *(const bf16x8*)&Xt[sw32(16*w4 + c, ks*4 + qd)];
    #pragma unroll
    for (int nc = 0; nc < 4; ++nc) {
      bf16x8 bf = *(const bf16x8*)&Wtile[sw32(nc*16 + c, ks*4 + qd)];
      sc[nc] = __builtin_amdgcn_mfma_f32_16x16x32_bf16(xa, bf, sc[nc], 0, 0, 0);
    }
  }
  #pragma unroll
  for (int nc = 0; nc < 4; ++nc)
    #pragma unroll
    for (int r = 0; r < 4; ++r)
      obase[(size_t)(n0 + 16*w4 + qd*4 + r)*D_ + e0 + nc*16 + c] = f2bf(sc[nc][r]);
}

// ---------------------------------------------------------------------------
// Kernel A2: transpose V (bf16) [h][b][t][e] -> vT [h*4+b][e][t].
// grid (32, 4, 32), block 256. (unchanged)
// ---------------------------------------------------------------------------
__global__ __launch_bounds__(256) void vtrans_kernel(
    const unsigned short* __restrict__ vb, unsigned short* __restrict__ vT)
{
  __shared__ unsigned short tile[64][72];
  const int tid = threadIdx.x;
  const int t0 = blockIdx.x * 64, e0 = blockIdx.y * 64;
  const int h = blockIdx.z >> 2, b = blockIdx.z & 3;
  const size_t in_base = (size_t)h*N_*D_ + (size_t)b*S_*D_;
  {
    int r = tid >> 2, c16 = (tid & 3) * 16;
    const unsigned short* src = vb + in_base + (size_t)(t0 + r)*D_ + e0 + c16;
    *(u16x8*)&tile[r][c16]     = *(const u16x8*)(src);
    *(u16x8*)&tile[r][c16 + 8] = *(const u16x8*)(src + 8);
  }
  __syncthreads();
  {
    int er = tid >> 2, tt = (tid & 3) * 16;
    u16x8 o0, o1;
    #pragma unroll
    for (int j = 0; j < 8; ++j) { o0[j] = tile[tt+j][er]; o1[j] = tile[tt+8+j][er]; }
    unsigned short* dst = vT + ((size_t)(h*4 + b)*D_ + e0 + er)*S_ + t0 + tt;
    *(u16x8*)(dst)     = o0;
    *(u16x8*)(dst + 8) = o1;
  }
}

// ---------------------------------------------------------------------------
// Kernel B1 (v11): attention O + L. Swapped QK, permuted K staging,
// in-register P via cvt_pk, XCD-pinned 1-D grid. (unchanged, verified 163 us)
// LDS 66 KB -> 2 blocks/CU. grid 512 (1-D), block 256.
// ---------------------------------------------------------------------------
__global__ __launch_bounds__(256, 2) void attn_ol_kernel(
    const unsigned short* __restrict__ qb, const unsigned short* __restrict__ kb,
    const unsigned short* __restrict__ vT, unsigned short* __restrict__ zcatb,
    float* __restrict__ Lws)
{
  __shared__ unsigned short Kt[2][32*32*8];   // 2 x 16 KB, swizzled 512B rows
  __shared__ unsigned short Vt[2][16*544];    // 2 x 17408 B, padded-chunk + perm
  const int tid = threadIdx.x;
  const int w = tid >> 6, lane = tid & 63;
  const int c = lane & 15, qd = lane >> 4;
  // XCD-pinned decode: group g = (h,b) pair; all 16 s-blocks of g share XCD.
  const int wg = blockIdx.x;
  const int xcd = wg & 7;
  const int slot = wg >> 3;          // 0..63
  const int j = slot & 15;           // s-block index
  const int gg = slot >> 4;          // 0..3
  const int g = gg*8 + xcd;          // 0..31, g%8 == xcd
  const int h = g >> 2, b = g & 3;
  const int s0 = j * 128;

  const size_t qkbase = (size_t)h*N_*D_ + (size_t)b*S_*D_;

  // Q frags for both m-tiles (held in registers all kernel); used as the
  // B-operand of the swapped QK MFMA (fragment layout is role-agnostic).
  bf16x8 qa[2][8];
  #pragma unroll
  for (int mi = 0; mi < 2; ++mi) {
    const unsigned short* qrow = qb + qkbase + (size_t)(s0 + 32*w + 16*mi + c)*D_ + qd*8;
    #pragma unroll
    for (int ks = 0; ks < 8; ++ks) qa[mi][ks] = *(const bf16x8*)(qrow + ks*32);
  }

  f32x4 o[2][16];
  #pragma unroll
  for (int mi = 0; mi < 2; ++mi)
    #pragma unroll
    for (int i = 0; i < 16; ++i) o[mi][i] = (f32x4){0.f,0.f,0.f,0.f};
  float Lp[2] = {0.f, 0.f};   // per-lane partial row-sum for q = 16*mi + c

  const char* kB = (const char*)(kb + qkbase);                       // key rows: 512 B
  const char* vB = (const char*)(vT + (size_t)(h*4 + b)*D_*S_);      // e rows: 4096 B

  // K staging: physical score-row r is loaded from logical key row L(r)
  // within the tile, so the swapped-QK output keys land grouped-by-8 per qd.
  // V chunk gq: e-rows gq*16..+16, 64 B per row (32 keys), lane l carries
  // (row r = l>>2, stored pos p = l&3) -> logical t-unit q = p ^ ((r>>1)&3).
  #define STAGE_OL(kt_, bi_)                                                   \
    {                                                                          \
      _Pragma("unroll")                                                        \
      for (int i = 0; i < 4; ++i) {                                            \
        int gq = w*4 + i;                                                      \
        int r = 2*gq + (lane >> 5);                                            \
        int Lg = ((r >> 2) & 3)*8 + (r >> 4)*4 + (r & 3);                      \
        int su = lane & 31;                                                    \
        int u = (su & 24) | ((su & 7) ^ (r & 7));                              \
        glds16(kB + ((size_t)(kt_)*32 + Lg)*512 + u*16, &Kt[bi_][gq*512]);     \
      }                                                                        \
      _Pragma("unroll")                                                        \
      for (int i = 0; i < 4; ++i) {                                            \
        int gq = w*4 + i;                                                      \
        int e = gq*16 + (lane >> 2);                                           \
        int qv = (lane & 3) ^ ((lane >> 3) & 3);                               \
        glds16(vB + (size_t)e*4096 + (size_t)(kt_)*64 + qv*16, &Vt[bi_][gq*544]);\
      }                                                                        \
    }

  STAGE_OL(0, 0);

  for (int kt = 0; kt < 64; ++kt) {
    const int bi = kt & 1;
    __syncthreads();                    // drains prefetch into buf bi
    if (kt + 1 < 64) STAGE_OL(kt + 1, bi ^ 1);

    // ---- QK (swapped): scores for 2 m-tiles x 32 keys; K-frag is the A
    // operand so the output is C[key][q] -> P-row is lane-local.
    f32x4 sc[2][2];
    #pragma unroll
    for (int mi = 0; mi < 2; ++mi)
      #pragma unroll
      for (int nc = 0; nc < 2; ++nc) sc[mi][nc] = (f32x4){0.f,0.f,0.f,0.f};
    #pragma unroll
    for (int ks = 0; ks < 8; ++ks) {
      bf16x8 kf0 = *(const bf16x8*)&Kt[bi][sw32(c,      ks*4 + qd)];
      bf16x8 kf1 = *(const bf16x8*)&Kt[bi][sw32(16 + c, ks*4 + qd)];
      #pragma unroll
      for (int mi = 0; mi < 2; ++mi) {
        sc[mi][0] = __builtin_amdgcn_mfma_f32_16x16x32_bf16(kf0, qa[mi][ks], sc[mi][0], 0, 0, 0);
        sc[mi][1] = __builtin_amdgcn_mfma_f32_16x16x32_bf16(kf1, qa[mi][ks], sc[mi][1], 0, 0, 0);
      }
    }
    // ---- exp (unnormalized), accumulate L, pack P in-register.
    // sc[mi][nc][r] = S[key = kt*32 + 8*qd + 4*nc + r][q = 16*mi + c], so the
    // PV A-frag dword j is pk(ex[j>>1][2*(j&1)], ex[j>>1][2*(j&1)+1]).
    bf16x8 pa[2];
    #pragma unroll
    for (int mi = 0; mi < 2; ++mi) {
      float ex[2][4];
      #pragma unroll
      for (int nc = 0; nc < 2; ++nc)
        #pragma unroll
        for (int r = 0; r < 4; ++r) {
          float p = __expf(sc[mi][nc][r]);
          ex[nc][r] = p;
          Lp[mi] += p;
        }
      union { unsigned u[4]; bf16x8 v; } cv;
      asm("v_cvt_pk_bf16_f32 %0, %1, %2" : "=v"(cv.u[0]) : "v"(ex[0][0]), "v"(ex[0][1]));
      asm("v_cvt_pk_bf16_f32 %0, %1, %2" : "=v"(cv.u[1]) : "v"(ex[0][2]), "v"(ex[0][3]));
      asm("v_cvt_pk_bf16_f32 %0, %1, %2" : "=v"(cv.u[2]) : "v"(ex[1][0]), "v"(ex[1][1]));
      asm("v_cvt_pk_bf16_f32 %0, %1, %2" : "=v"(cv.u[3]) : "v"(ex[1][2]), "v"(ex[1][3]));
      pa[mi] = cv.v;
    }
    // ---- PV: each V read feeds 2 MFMA; conflict-free padded-chunk layout
    #pragma unroll
    for (int ec = 0; ec < 16; ++ec) {
      bf16x8 vf = *(const bf16x8*)&Vt[bi][ec*544 + c*32 + (qd ^ ((c >> 1) & 3))*8];
      o[0][ec] = __builtin_amdgcn_mfma_f32_16x16x32_bf16(pa[0], vf, o[0][ec], 0, 0, 0);
      o[1][ec] = __builtin_amdgcn_mfma_f32_16x16x32_bf16(pa[1], vf, o[1][ec], 0, 0, 0);
    }
  }

  // ---- epilogue per m-tile: reduce L across qd-groups, store L,
  // redistribute 1/L to the O layout (rows qd*4+r), normalize, store zcat.
  #pragma unroll
  for (int mi = 0; mi < 2; ++mi) {
    float L = Lp[mi];
    L += __shfl_xor(L, 16);
    L += __shfl_xor(L, 32);          // all lanes now hold L for q = 16*mi + c
    if (qd == 0)
      Lws[(size_t)h*N_ + b*S_ + s0 + 32*w + 16*mi + c] = L;
    float il[4];
    #pragma unroll
    for (int r = 0; r < 4; ++r)
      il[r] = 1.0f / __shfl(L, (lane & 48) | (qd*4 + r));
    #pragma unroll
    for (int ec = 0; ec < 16; ++ec)
      #pragma unroll
      for (int r = 0; r < 4; ++r)
        zcatb[(size_t)(b*S_ + s0 + 32*w + 16*mi + qd*4 + r)*HD_ + h*D_ + ec*16 + c] =
            f2bf(o[mi][ec][r] * il[r]);
  }
  #undef STAGE_OL
}

// ---------------------------------------------------------------------------
// Kernel B2 (v15): attn_mean = (1/8) sum_h exp(s_h)/L_h, QK recompute.
// Round-8 change: v14's residency stayed at 2 blocks/CU because the unified
// VGPR+AGPR total (88 arch + ~48-64 acc) exceeded 128 -> 2-waves/SIMD bin
// (rocprof VGPR_Count excludes AGPRs; m69: waves halve at 64/128/256).
// v15 EARNS the 4-wave bin: block = 64 s-rows x 64 t-cols, each wave owns
// ONE 16-row m-tile. Live set: am[4][4]=16 + qa[8]=32 + sc[4]=16(acc) +
// il=4 + addr ~20 = ~90 total <= the 128 budget that launch_bounds(256,4)
// grants -> no spill (v13's failure was a ~160-reg live set vs that budget).
// Single-buffer Kt 32 KB (LDS cap 5 blocks). grid 4096 (1-D XCD-pinned by
// (b,t0): 32 s-blocks per group share the K slice), block 256.
// ---------------------------------------------------------------------------
__global__ __launch_bounds__(256, 4) void attn_mean_kernel(
    const unsigned short* __restrict__ qb, const unsigned short* __restrict__ kb,
    const float* __restrict__ Lws, float* __restrict__ out_attn)
{
  __shared__ unsigned short Kt[64*32*8];   // 32 KB single buffer
  const int tid = threadIdx.x;
  const int w = tid >> 6, lane = tid & 63;
  const int c = lane & 15, qd = lane >> 4;
  // XCD-pinned decode: group g = (b, t-block); 32 s-blocks of g share XCD.
  const int wg = blockIdx.x;
  const int xcd = wg & 7;
  const int slot = wg >> 3;          // 0..511
  const int j = slot & 31;           // s-block index (64 rows each)
  const int ggg = slot >> 5;         // 0..15
  const int g = ggg*8 + xcd;         // 0..127, g%8 == xcd
  const int b = g >> 5;
  const int t0 = (g & 31) * 64;
  const int s0 = j * 64;
  const int srow = s0 + 16*w;        // this wave's m-tile base row

  float am[4][4] = {};   // [nc][r]  (16 regs, held all kernel)

  #define STAGE_AM(h_)                                                         \
    {                                                                          \
      const char* kB = (const char*)(kb + (size_t)(h_)*N_*D_ + (size_t)b*S_*D_);\
      _Pragma("unroll")                                                        \
      for (int i = 0; i < 8; ++i) {                                            \
        int gq = w*8 + i;                                                      \
        int r = 2*gq + (lane >> 5);                                            \
        int su = lane & 31;                                                    \
        int u = (su & 24) | ((su & 7) ^ (r & 7));                              \
        glds16(kB + ((size_t)t0 + r)*512 + u*16, &Kt[gq*512]);                 \
      }                                                                        \
    }

  STAGE_AM(0);

  for (int h = 0; h < 8; ++h) {
    // Q frags and 1/L for head h: global loads issued while the K stage for
    // this head is in flight (both drained by the barrier below).
    bf16x8 qa[8];
    const size_t base = (size_t)h*N_*D_ + (size_t)b*S_*D_;
    const unsigned short* qrow = qb + base + (size_t)(srow + c)*D_ + qd*8;
    #pragma unroll
    for (int ks = 0; ks < 8; ++ks) qa[ks] = *(const bf16x8*)(qrow + ks*32);
    float il[4];
    #pragma unroll
    for (int r = 0; r < 4; ++r)
      il[r] = 0.125f / Lws[(size_t)h*N_ + b*S_ + srow + qd*4 + r];

    __syncthreads();                 // stage(h) drained (vmcnt0 before barrier)

    f32x4 sc[4];
    #pragma unroll
    for (int nc = 0; nc < 4; ++nc) sc[nc] = (f32x4){0.f,0.f,0.f,0.f};
    #pragma unroll
    for (int ks = 0; ks < 8; ++ks) {
      #pragma unroll
      for (int nc = 0; nc < 4; ++nc) {
        bf16x8 kf = *(const bf16x8*)&Kt[sw32(nc*16 + c, ks*4 + qd)];
        sc[nc] = __builtin_amdgcn_mfma_f32_16x16x32_bf16(qa[ks], kf, sc[nc], 0, 0, 0);
      }
    }

    // All waves done reading Kt -> barrier, then issue next head's stage so
    // the glds16s fly under the exp/accumulate VALU work below.
    if (h + 1 < 8) {
      __syncthreads();
      STAGE_AM(h + 1);
    }

    #pragma unroll
    for (int nc = 0; nc < 4; ++nc)
      #pragma unroll
      for (int r = 0; r < 4; ++r)
        am[nc][r] += __expf(sc[nc][r]) * il[r];
  }
  #pragma unroll
  for (int nc = 0; nc < 4; ++nc)
    #pragma unroll
    for (int r = 0; r < 4; ++r)
      out_attn[(size_t)(b*S_ + srow + qd*4 + r)*S_ + t0 + nc*16 + c] = am[nc][r];
  #undef STAGE_AM
}

// ---------------------------------------------------------------------------
// Kernel C: z = zcat @ Wz + bz; r = z + X; z1 = LN1(r) -> bf16 out for MLP.
// grid 256, block 256. (unchanged)
// ---------------------------------------------------------------------------
__global__ __launch_bounds__(256) void wz_ln1_kernel(
    const unsigned short* __restrict__ zcatb, const unsigned short* __restrict__ Wzt,
    const float* __restrict__ bz, const float* __restrict__ X,
    const float* __restrict__ g1, const float* __restrict__ be1,
    unsigned short* __restrict__ z1b)
{
  __shared__ unsigned short At[32*16*8];     // 8 KB
  __shared__ unsigned short Wt2[256*16*8];   // 64 KB
  __shared__ float redS[2][32], redQ[2][32];
  const int tid = threadIdx.x;
  const int w4 = tid >> 6, lane = tid & 63;
  const int c = lane & 15, qd = lane >> 4;
  const int n0 = blockIdx.x * 32;
  const int msub = w4 & 1, ehalf = w4 >> 1;

  f32x4 acc[8];
  #pragma unroll
  for (int nc = 0; nc < 8; ++nc) acc[nc] = (f32x4){0.f,0.f,0.f,0.f};

  for (int kc = 0; kc < 16; ++kc) {
    {
      const char* ab = (const char*)zcatb + (size_t)n0*4096 + (size_t)kc*256;
      #pragma unroll
      for (int i = 0; i < 2; ++i) {
        int g = w4*2 + i;
        int r = g*4 + (lane >> 4);
        int su = lane & 15;
        int u = (su & 8) | ((su & 7) ^ (r & 7));
        glds16(ab + (size_t)r*4096 + u*16, &At[g*512]);
      }
      const char* wb = (const char*)Wzt + (size_t)kc*256;
      #pragma unroll
      for (int i = 0; i < 16; ++i) {
        int g = w4*16 + i;
        int e = g*4 + (lane >> 4);
        int su = lane & 15;
        int u = (su & 8) | ((su & 7) ^ (e & 7));
        glds16(wb + (size_t)e*4096 + u*16, &Wt2[g*512]);
      }
    }
    __syncthreads();
    #pragma unroll
    for (int ks = 0; ks < 4; ++ks) {
      bf16x8 a = *(const bf16x8*)&At[sw16(msub*16 + c, ks*4 + qd)];
      #pragma unroll
      for (int nc = 0; nc < 8; ++nc) {
        bf16x8 bv = *(const bf16x8*)&Wt2[sw16(ehalf*128 + nc*16 + c, ks*4 + qd)];
        acc[nc] = __builtin_amdgcn_mfma_f32_16x16x32_bf16(a, bv, acc[nc], 0, 0, 0);
      }
    }
    __syncthreads();
  }

  float vals[8][4];
  float sum_[4] = {0.f,0.f,0.f,0.f}, sq_[4] = {0.f,0.f,0.f,0.f};
  #pragma unroll
  for (int nc = 0; nc < 8; ++nc) {
    int e = ehalf*128 + nc*16 + c;
    #pragma unroll
    for (int r = 0; r < 4; ++r) {
      int n = n0 + msub*16 + qd*4 + r;
      float v = acc[nc][r] + bz[e] + X[(size_t)n*D_ + e];
      vals[nc][r] = v;
      sum_[r] += v; sq_[r] += v*v;
    }
  }
  #pragma unroll
  for (int off = 1; off < 16; off <<= 1) {
    #pragma unroll
    for (int r = 0; r < 4; ++r) {
      sum_[r] += __shfl_xor(sum_[r], off);
      sq_[r]  += __shfl_xor(sq_[r],  off);
    }
  }
  if (c == 0) {
    #pragma unroll
    for (int r = 0; r < 4; ++r) {
      redS[ehalf][msub*16 + qd*4 + r] = sum_[r];
      redQ[ehalf][msub*16 + qd*4 + r] = sq_[r];
    }
  }
  __syncthreads();
  #pragma unroll
  for (int r = 0; r < 4; ++r) {
    int lr = msub*16 + qd*4 + r;
    float Sv = redS[0][lr] + redS[1][lr];
    float Qv = redQ[0][lr] + redQ[1][lr];
    float mean = Sv * (1.0f/D_);
    float var  = Qv * (1.0f/D_) - mean*mean;
    float rstd = rsqrtf(var + EPS);
    int n = n0 + lr;
    #pragma unroll
    for (int nc = 0; nc < 8; ++nc) {
      int e = ehalf*128 + nc*16 + c;
      z1b[(size_t)n*D_ + e] = f2bf((vals[nc][r] - mean)*rstd*g1[e] + be1[e]);
    }
  }
}

// ---------------------------------------------------------------------------
// Kernel D1: h = relu(z1 @ W1 + b1), bf16 out. grid (128, 8), block 256.
// (unchanged)
// ---------------------------------------------------------------------------
__global__ __launch_bounds__(256) void mlp1_kernel(
    const unsigned short* __restrict__ z1b, const unsigned short* __restrict__ W1t,
    const float* __restrict__ b1, unsigned short* __restrict__ hbuf)
{
  __shared__ unsigned short At[64*32*8];     // 32 KB
  __shared__ unsigned short Bt[64*32*8];     // 32 KB
  const int tid = threadIdx.x;
  const int w4 = tid >> 6, lane = tid & 63;
  const int c = lane & 15, qd = lane >> 4;
  const int n0 = blockIdx.x * 64;
  const int f0 = blockIdx.y * 64;

  {
    const char* ag = (const char*)z1b + (size_t)n0*512;
    const char* bg = (const char*)W1t + (size_t)f0*512;
    #pragma unroll
    for (int i = 0; i < 8; ++i) {
      int g = w4*8 + i;
      int r = 2*g + (lane >> 5);
      int su = lane & 31;
      int u = (su & 24) | ((su & 7) ^ (r & 7));
      glds16(ag + (size_t)r*512 + u*16, &At[g*512]);
      glds16(bg + (size_t)r*512 + u*16, &Bt[g*512]);
    }
  }
  __syncthreads();

  f32x4 sc[4];
  #pragma unroll
  for (int nc = 0; nc < 4; ++nc) sc[nc] = (f32x4){0.f,0.f,0.f,0.f};
  #pragma unroll
  for (int ks = 0; ks < 8; ++ks) {
    bf16x8 xa = *(const bf16x8*)&At[sw32(16*w4 + c, ks*4 + qd)];
    #pragma unroll
    for (int nc = 0; nc < 4; ++nc) {
      bf16x8 bf = *(const bf16x8*)&Bt[sw32(nc*16 + c, ks*4 + qd)];
      sc[nc] = __builtin_amdgcn_mfma_f32_16x16x32_bf16(xa, bf, sc[nc], 0, 0, 0);
    }
  }
  #pragma unroll
  for (int nc = 0; nc < 4; ++nc) {
    int f = f0 + nc*16 + c;
    float bias = b1[f];
    #pragma unroll
    for (int r = 0; r < 4; ++r)
      hbuf[(size_t)(n0 + 16*w4 + qd*4 + r)*FD_ + f] = f2bf(fmaxf(sc[nc][r] + bias, 0.f));
  }
}

// ---------------------------------------------------------------------------
// Kernel D2: z_ff = h @ W2 + b2; out = LN2(z_ff + z1). grid 256, block 256.
// (unchanged)
// ---------------------------------------------------------------------------
__global__ __launch_bounds__(256) void mlp2_kernel(
    const unsigned short* __restrict__ hbuf, const unsigned short* __restrict__ W2t,
    const float* __restrict__ b2, const unsigned short* __restrict__ z1b,
    const float* __restrict__ g2, const float* __restrict__ be2,
    float* __restrict__ out)
{
  __shared__ unsigned short At[32*16*8];     // 8 KB
  __shared__ unsigned short Wt2[256*16*8];   // 64 KB
  __shared__ float redS[2][32], redQ[2][32];
  const int tid = threadIdx.x;
  const int w4 = tid >> 6, lane = tid & 63;
  const int c = lane & 15, qd = lane >> 4;
  const int n0 = blockIdx.x * 32;
  const int msub = w4 & 1, ehalf = w4 >> 1;

  f32x4 acc[8];
  #pragma unroll
  for (int nc = 0; nc < 8; ++nc) acc[nc] = (f32x4){0.f,0.f,0.f,0.f};

  for (int kc = 0; kc < 4; ++kc) {
    {
      const char* ab = (const char*)hbuf + (size_t)n0*1024 + (size_t)kc*256;
      #pragma unroll
      for (int i = 0; i < 2; ++i) {
        int g = w4*2 + i;
        int r = g*4 + (lane >> 4);
        int su = lane & 15;
        int u = (su & 8) | ((su & 7) ^ (r & 7));
        glds16(ab + (size_t)r*1024 + u*16, &At[g*512]);
      }
      const char* wb = (const char*)W2t + (size_t)kc*256;
      #pragma unroll
      for (int i = 0; i < 16; ++i) {
        int g = w4*16 + i;
        int e = g*4 + (lane >> 4);
        int su = lane & 15;
        int u = (su & 8) | ((su & 7) ^ (e & 7));
        glds16(wb + (size_t)e*1024 + u*16, &Wt2[g*512]);
      }
    }
    __syncthreads();
    #pragma unroll
    for (int ks = 0; ks < 4; ++ks) {
      bf16x8 a = *(const bf16x8*)&At[sw16(msub*16 + c, ks*4 + qd)];
      #pragma unroll
      for (int nc = 0; nc < 8; ++nc) {
        bf16x8 bv = *(const bf16x8*)&Wt2[sw16(ehalf*128 + nc*16 + c, ks*4 + qd)];
        acc[nc] = __builtin_amdgcn_mfma_f32_16x16x32_bf16(a, bv, acc[nc], 0, 0, 0);
      }
    }
    __syncthreads();
  }

  float vals[8][4];
  float sum_[4] = {0.f,0.f,0.f,0.f}, sq_[4] = {0.f,0.f,0.f,0.f};
  #pragma unroll
  for (int nc = 0; nc < 8; ++nc) {
    int e = ehalf*128 + nc*16 + c;
    #pragma unroll
    for (int r = 0; r < 4; ++r) {
      int n = n0 + msub*16 + qd*4 + r;
      float v = acc[nc][r] + b2[e] + bf2f(z1b[(size_t)n*D_ + e]);
      vals[nc][r] = v;
      sum_[r] += v; sq_[r] += v*v;
    }
  }
  #pragma unroll
  for (int off = 1; off < 16; off <<= 1) {
    #pragma unroll
    for (int r = 0; r < 4; ++r) {
      sum_[r] += __shfl_xor(sum_[r], off);
      sq_[r]  += __shfl_xor(sq_[r],  off);
    }
  }
  if (c == 0) {
    #pragma unroll
    for (int r = 0; r < 4; ++r) {
      redS[ehalf][msub*16 + qd*4 + r] = sum_[r];
      redQ[ehalf][msub*16 + qd*4 + r] = sq_[r];
    }
  }
  __syncthreads();
  #pragma unroll
  for (int r = 0; r < 4; ++r) {
    int lr = msub*16 + qd*4 + r;
    float Sv = redS[0][lr] + redS[1][lr];
    float Qv = redQ[0][lr] + redQ[1][lr];
    float mean = Sv * (1.0f/D_);
    float var  = Qv * (1.0f/D_) - mean*mean;
    float rstd = rsqrtf(var + EPS);
    int n = n0 + lr;
    #pragma unroll
    for (int nc = 0; nc < 8; ++nc) {
      int e = ehalf*128 + nc*16 + c;
      out[(size_t)n*D_ + e] = (vals[nc][r] - mean)*rstd*g2[e] + be2[e];
    }
  }
}

// ---------------------------------------------------------------------------
// ws layout: Xb | Wt | Wzt | W1t | W2t | qb kb vb vT | Lws | zcatb | z1b | hbuf
// d_out: z [N*D] then attn_mean [B*S*S].
// ---------------------------------------------------------------------------
extern "C" void kernel_launch(void* const* d_in, const int* in_sizes, int n_in,
                              void* d_out, int out_size, void* d_ws, size_t ws_size,
                              hipStream_t stream)
{
  (void)in_sizes; (void)n_in; (void)out_size; (void)ws_size;
  const float* X   = (const float*)d_in[0];
  const float* Wq  = (const float*)d_in[1];
  const float* Wk  = (const float*)d_in[2];
  const float* Wv  = (const float*)d_in[3];
  const float* Wz  = (const float*)d_in[4];
  const float* bz  = (const float*)d_in[5];
  const float* W1  = (const float*)d_in[6];
  const float* b1  = (const float*)d_in[7];
  const float* W2  = (const float*)d_in[8];
  const float* b2  = (const float*)d_in[9];
  const float* g1  = (const float*)d_in[10];
  const float* be1 = (const float*)d_in[11];
  const float* g2  = (const float*)d_in[12];
  const float* be2 = (const float*)d_in[13];

  char* p = (char*)d_ws;
  unsigned short* Xbb  = (unsigned short*)p; p += (size_t)N_*D_*2;
  unsigned short* Wtb  = (unsigned short*)p; p += (size_t)24*D_*D_*2;
  unsigned short* Wztb = (unsigned short*)p; p += (size_t)D_*HD_*2;
  unsigned short* W1tb = (unsigned short*)p; p += (size_t)FD_*D_*2;
  unsigned short* W2tb = (unsigned short*)p; p += (size_t)D_*FD_*2;
  unsigned short* qbuf = (unsigned short*)p; p += (size_t)H_*N_*D_*2;
  unsigned short* kbuf = (unsigned short*)p; p += (size_t)H_*N_*D_*2;
  unsigned short* vbuf = (unsigned short*)p; p += (size_t)H_*N_*D_*2;
  unsigned short* vTb  = (unsigned short*)p; p += (size_t)H_*N_*D_*2;
  float* Lws   = (float*)p; p += (size_t)H_*N_*4;
  unsigned short* zcatb = (unsigned short*)p; p += (size_t)N_*HD_*2;
  unsigned short* z1b   = (unsigned short*)p; p += (size_t)N_*D_*2;
  unsigned short* hbuf  = (unsigned short*)p;

  float* out_z    = (float*)d_out;
  float* out_attn = out_z + (size_t)N_*D_;

  cast_x_kernel<<<N_*D_/(256*8), 256, 0, stream>>>(X, Xbb);

  dim3 gW(4, 4, 24);
  prep_w_kernel<<<gW, 256, 0, stream>>>(Wq, Wk, Wv, Wtb);

  { dim3 g(HD_/64, D_/64);  tcast_kernel<<<g, 256, 0, stream>>>(Wz, Wztb, HD_, D_); }
  { dim3 g(D_/64, FD_/64);  tcast_kernel<<<g, 256, 0, stream>>>(W1, W1tb, D_, FD_); }
  { dim3 g(FD_/64, D_/64);  tcast_kernel<<<g, 256, 0, stream>>>(W2, W2tb, FD_, D_); }

  dim3 gA(N_/64, D_/64, 24);
  qkv_kernel<<<gA, 256, 0, stream>>>(Xbb, Wtb, qbuf, kbuf, vbuf);

  dim3 gT(S_/64, D_/64, H_*B_);
  vtrans_kernel<<<gT, 256, 0, stream>>>(vbuf, vTb);

  attn_ol_kernel<<<512, 256, 0, stream>>>(qbuf, kbuf, vTb, zcatb, Lws);

  attn_mean_kernel<<<4096, 256, 0, stream>>>(qbuf, kbuf, Lws, out_attn);

  wz_ln1_kernel<<<N_/32, 256, 0, stream>>>(zcatb, Wztb, bz, X, g1, be1, z1b);

  dim3 gM1(N_/64, FD_/64);
  mlp1_kernel<<<gM1, 256, 0, stream>>>(z1b, W1tb, b1, hbuf);

  mlp2_kernel<<<N_/32, 256, 0, stream>>>(hbuf, W2tb, b2, z1b, g2, be2, out_z);
}

// Round 9
// 527.019 us; speedup vs baseline: 1.0491x; 1.0491x over previous
//
#include <hip/hip_runtime.h>
#include <cstdint>
#include <cstddef>

// Problem constants (match reference)
#define B_  4
#define S_  2048
#define D_  256
#define H_  8
#define FD_ 512              // F*D
#define N_  (B_*S_)          // 8192 rows
#define HD_ (H_*D_)          // 2048 concat dim
#define EPS 1e-5f

typedef __attribute__((ext_vector_type(8))) short bf16x8;   // 8 bf16 in 4 VGPRs
typedef __attribute__((ext_vector_type(8))) unsigned short u16x8;
typedef __attribute__((ext_vector_type(4))) float f32x4;

__device__ __forceinline__ unsigned short f2bf(float f) {
  union { float f; unsigned u; } x; x.f = f;
  unsigned u = x.u;
  return (unsigned short)((u + 0x7FFFu + ((u >> 16) & 1u)) >> 16);  // RNE
}
__device__ __forceinline__ float bf2f(unsigned short h) {
  union { unsigned u; float f; } x; x.u = ((unsigned)h) << 16; return x.f;
}

// Coalesced async global->LDS, 16 B/lane; LDS dest = wave-uniform base +
// lane*16 (m104/m108); gptr is per-lane (lets us permute the source).
__device__ __forceinline__ void glds16(const void* gptr, void* ldsptr) {
  __builtin_amdgcn_global_load_lds(
      (__attribute__((address_space(1))) void*)gptr,
      (__attribute__((address_space(3))) void*)ldsptr,
      16, 0, 0);
}

// XOR-swizzled LDS tile addressing (in shorts; unit = 16 B).
// Row r, unit u stored at (u&~7)|((u&7)^(r&7)) -> conflict-free b128 phases.
__device__ __forceinline__ int sw32(int row, int u) {      // 32 units/row (512 B)
  return (row*32 + ((u & 24) | ((u & 7) ^ (row & 7)))) * 8;
}
__device__ __forceinline__ int sw16(int row, int u) {      // 16 units/row (256 B)
  return (row*16 + ((u & 8) | ((u & 7) ^ (row & 7)))) * 8;
}

// ---------------------------------------------------------------------------
// Prep 1: cast X fp32 -> bf16. grid 1024, block 256.
// ---------------------------------------------------------------------------
__global__ __launch_bounds__(256) void cast_x_kernel(
    const float* __restrict__ X, unsigned short* __restrict__ Xb)
{
  const size_t i8 = ((size_t)blockIdx.x * 256 + threadIdx.x) * 8;
  float4 a = *(const float4*)&X[i8];
  float4 b = *(const float4*)&X[i8 + 4];
  u16x8 o;
  o[0]=f2bf(a.x); o[1]=f2bf(a.y); o[2]=f2bf(a.z); o[3]=f2bf(a.w);
  o[4]=f2bf(b.x); o[5]=f2bf(b.y); o[6]=f2bf(b.z); o[7]=f2bf(b.w);
  *(u16x8*)&Xb[i8] = o;
}

// ---------------------------------------------------------------------------
// Prep 2: Wq/Wk/Wv [h][d][e] fp32 -> Wt bf16 [w][e][d] (transposed), scale
// 0.25 folded into q,k. grid (4,4,24), block 256.
// ---------------------------------------------------------------------------
__global__ __launch_bounds__(256) void prep_w_kernel(
    const float* __restrict__ Wq, const float* __restrict__ Wk,
    const float* __restrict__ Wv, unsigned short* __restrict__ Wt)
{
  __shared__ float tile[64][65];
  const int tid = threadIdx.x;
  const int d0 = blockIdx.x * 64, e0 = blockIdx.y * 64;
  const int w = blockIdx.z;
  const float* src;
  float scale;
  if (w < 8)       { src = Wq + (size_t)w*D_*D_;      scale = 0.25f; }
  else if (w < 16) { src = Wk + (size_t)(w-8)*D_*D_;  scale = 0.25f; }
  else             { src = Wv + (size_t)(w-16)*D_*D_; scale = 1.0f;  }
  {
    int r = tid >> 2, c16 = (tid & 3) * 16;
    const float* s = src + (size_t)(d0 + r)*D_ + e0 + c16;
    #pragma unroll
    for (int u = 0; u < 4; ++u) *(float4*)&tile[r][c16 + u*4] = *(const float4*)(s + u*4);
  }
  __syncthreads();
  {
    int er = tid >> 2, dc = (tid & 3) * 16;
    u16x8 o0, o1;
    #pragma unroll
    for (int j = 0; j < 8; ++j) {
      o0[j] = f2bf(tile[dc + j][er] * scale);
      o1[j] = f2bf(tile[dc + 8 + j][er] * scale);
    }
    unsigned short* dst = Wt + ((size_t)w*D_ + e0 + er)*D_ + d0 + dc;
    *(u16x8*)(dst)     = o0;
    *(u16x8*)(dst + 8) = o1;
  }
}

// ---------------------------------------------------------------------------
// Prep 3 (generic): transpose-cast src fp32 [R][C] -> dst bf16 [C][R].
// grid (R/64, C/64), block 256. Used for Wz, W1, W2.
// ---------------------------------------------------------------------------
__global__ __launch_bounds__(256) void tcast_kernel(
    const float* __restrict__ src, unsigned short* __restrict__ dst,
    int R, int C)
{
  __shared__ float tile[64][65];
  const int tid = threadIdx.x;
  const int r0 = blockIdx.x * 64, c0 = blockIdx.y * 64;
  {
    int r = tid >> 2, c16 = (tid & 3) * 16;
    const float* s = src + (size_t)(r0 + r)*C + c0 + c16;
    #pragma unroll
    for (int u = 0; u < 4; ++u) *(float4*)&tile[r][c16 + u*4] = *(const float4*)(s + u*4);
  }
  __syncthreads();
  {
    int cr = tid >> 2, rc = (tid & 3) * 16;
    u16x8 o0, o1;
    #pragma unroll
    for (int j = 0; j < 8; ++j) {
      o0[j] = f2bf(tile[rc + j][cr]);
      o1[j] = f2bf(tile[rc + 8 + j][cr]);
    }
    unsigned short* d = dst + (size_t)(c0 + cr)*R + r0 + rc;
    *(u16x8*)(d)     = o0;
    *(u16x8*)(d + 8) = o1;
  }
}

// ---------------------------------------------------------------------------
// Kernel A: QKV projections, MFMA bf16, swizzled LDS. 24 GEMMs M=8192 N=256
// K=256. grid (128, 4, 24), block 256. (unchanged)
// ---------------------------------------------------------------------------
__global__ __launch_bounds__(256) void qkv_kernel(
    const unsigned short* __restrict__ Xb, const unsigned short* __restrict__ Wt,
    unsigned short* __restrict__ q, unsigned short* __restrict__ k,
    unsigned short* __restrict__ v)
{
  __shared__ unsigned short Xt[64*32*8];     // 32 KB
  __shared__ unsigned short Wtile[64*32*8];  // 32 KB
  const int tid = threadIdx.x;
  const int w4 = tid >> 6, lane = tid & 63;
  const int c = lane & 15, qd = lane >> 4;
  const int n0 = blockIdx.x * 64;
  const int e0 = blockIdx.y * 64;
  const int w  = blockIdx.z;

  unsigned short* obase;
  if (w < 8)       obase = q + (size_t)w*N_*D_;
  else if (w < 16) obase = k + (size_t)(w-8)*N_*D_;
  else             obase = v + (size_t)(w-16)*N_*D_;

  {
    const char* xg = (const char*)Xb + (size_t)n0*512;
    const char* wg = (const char*)Wt + ((size_t)w*D_ + e0)*512;
    #pragma unroll
    for (int i = 0; i < 8; ++i) {
      int g = w4*8 + i;
      int r = 2*g + (lane >> 5);
      int su = lane & 31;
      int u = (su & 24) | ((su & 7) ^ (r & 7));
      glds16(xg + (size_t)r*512 + u*16, &Xt[g*512]);
      glds16(wg + (size_t)r*512 + u*16, &Wtile[g*512]);
    }
  }
  __syncthreads();

  f32x4 sc[4];
  #pragma unroll
  for (int nc = 0; nc < 4; ++nc) sc[nc] = (f32x4){0.f,0.f,0.f,0.f};
  #pragma unroll
  for (int ks = 0; ks < 8; ++ks) {
    bf16x8 xa = *(const bf16x8*)&Xt[sw32(16*w4 + c, ks*4 + qd)];
    #pragma unroll
    for (int nc = 0; nc < 4; ++nc) {
      bf16x8 bf = *(const bf16x8*)&Wtile[sw32(nc*16 + c, ks*4 + qd)];
      sc[nc] = __builtin_amdgcn_mfma_f32_16x16x32_bf16(xa, bf, sc[nc], 0, 0, 0);
    }
  }
  #pragma unroll
  for (int nc = 0; nc < 4; ++nc)
    #pragma unroll
    for (int r = 0; r < 4; ++r)
      obase[(size_t)(n0 + 16*w4 + qd*4 + r)*D_ + e0 + nc*16 + c] = f2bf(sc[nc][r]);
}

// ---------------------------------------------------------------------------
// Kernel A2: transpose V (bf16) [h][b][t][e] -> vT [h*4+b][e][t].
// grid (32, 4, 32), block 256. (unchanged)
// ---------------------------------------------------------------------------
__global__ __launch_bounds__(256) void vtrans_kernel(
    const unsigned short* __restrict__ vb, unsigned short* __restrict__ vT)
{
  __shared__ unsigned short tile[64][72];
  const int tid = threadIdx.x;
  const int t0 = blockIdx.x * 64, e0 = blockIdx.y * 64;
  const int h = blockIdx.z >> 2, b = blockIdx.z & 3;
  const size_t in_base = (size_t)h*N_*D_ + (size_t)b*S_*D_;
  {
    int r = tid >> 2, c16 = (tid & 3) * 16;
    const unsigned short* src = vb + in_base + (size_t)(t0 + r)*D_ + e0 + c16;
    *(u16x8*)&tile[r][c16]     = *(const u16x8*)(src);
    *(u16x8*)&tile[r][c16 + 8] = *(const u16x8*)(src + 8);
  }
  __syncthreads();
  {
    int er = tid >> 2, tt = (tid & 3) * 16;
    u16x8 o0, o1;
    #pragma unroll
    for (int j = 0; j < 8; ++j) { o0[j] = tile[tt+j][er]; o1[j] = tile[tt+8+j][er]; }
    unsigned short* dst = vT + ((size_t)(h*4 + b)*D_ + e0 + er)*S_ + t0 + tt;
    *(u16x8*)(dst)     = o0;
    *(u16x8*)(dst + 8) = o1;
  }
}

// ---------------------------------------------------------------------------
// Kernel B1 (v11, verified 163 us / FETCH 49 MB): attention O + L.
// Swapped QK, permuted K staging, in-register P via cvt_pk, XCD-pinned
// 1-D grid. LDS 66 KB -> 2 blocks/CU. grid 512 (1-D), block 256.
// ---------------------------------------------------------------------------
__global__ __launch_bounds__(256, 2) void attn_ol_kernel(
    const unsigned short* __restrict__ qb, const unsigned short* __restrict__ kb,
    const unsigned short* __restrict__ vT, unsigned short* __restrict__ zcatb,
    float* __restrict__ Lws)
{
  __shared__ unsigned short Kt[2][32*32*8];   // 2 x 16 KB, swizzled 512B rows
  __shared__ unsigned short Vt[2][16*544];    // 2 x 17408 B, padded-chunk + perm
  const int tid = threadIdx.x;
  const int w = tid >> 6, lane = tid & 63;
  const int c = lane & 15, qd = lane >> 4;
  // XCD-pinned decode: group g = (h,b) pair; all 16 s-blocks of g share XCD.
  const int wg = blockIdx.x;
  const int xcd = wg & 7;
  const int slot = wg >> 3;          // 0..63
  const int j = slot & 15;           // s-block index
  const int gg = slot >> 4;          // 0..3
  const int g = gg*8 + xcd;          // 0..31, g%8 == xcd
  const int h = g >> 2, b = g & 3;
  const int s0 = j * 128;

  const size_t qkbase = (size_t)h*N_*D_ + (size_t)b*S_*D_;

  // Q frags for both m-tiles (held in registers all kernel); used as the
  // B-operand of the swapped QK MFMA (fragment layout is role-agnostic).
  bf16x8 qa[2][8];
  #pragma unroll
  for (int mi = 0; mi < 2; ++mi) {
    const unsigned short* qrow = qb + qkbase + (size_t)(s0 + 32*w + 16*mi + c)*D_ + qd*8;
    #pragma unroll
    for (int ks = 0; ks < 8; ++ks) qa[mi][ks] = *(const bf16x8*)(qrow + ks*32);
  }

  f32x4 o[2][16];
  #pragma unroll
  for (int mi = 0; mi < 2; ++mi)
    #pragma unroll
    for (int i = 0; i < 16; ++i) o[mi][i] = (f32x4){0.f,0.f,0.f,0.f};
  float Lp[2] = {0.f, 0.f};   // per-lane partial row-sum for q = 16*mi + c

  const char* kB = (const char*)(kb + qkbase);                       // key rows: 512 B
  const char* vB = (const char*)(vT + (size_t)(h*4 + b)*D_*S_);      // e rows: 4096 B

  // K staging: physical score-row r is loaded from logical key row L(r)
  // within the tile, so the swapped-QK output keys land grouped-by-8 per qd.
  // V chunk gq: e-rows gq*16..+16, 64 B per row (32 keys), lane l carries
  // (row r = l>>2, stored pos p = l&3) -> logical t-unit q = p ^ ((r>>1)&3).
  #define STAGE_OL(kt_, bi_)                                                   \
    {                                                                          \
      _Pragma("unroll")                                                        \
      for (int i = 0; i < 4; ++i) {                                            \
        int gq = w*4 + i;                                                      \
        int r = 2*gq + (lane >> 5);                                            \
        int Lg = ((r >> 2) & 3)*8 + (r >> 4)*4 + (r & 3);                      \
        int su = lane & 31;                                                    \
        int u = (su & 24) | ((su & 7) ^ (r & 7));                              \
        glds16(kB + ((size_t)(kt_)*32 + Lg)*512 + u*16, &Kt[bi_][gq*512]);     \
      }                                                                        \
      _Pragma("unroll")                                                        \
      for (int i = 0; i < 4; ++i) {                                            \
        int gq = w*4 + i;                                                      \
        int e = gq*16 + (lane >> 2);                                           \
        int qv = (lane & 3) ^ ((lane >> 3) & 3);                               \
        glds16(vB + (size_t)e*4096 + (size_t)(kt_)*64 + qv*16, &Vt[bi_][gq*544]);\
      }                                                                        \
    }

  STAGE_OL(0, 0);

  for (int kt = 0; kt < 64; ++kt) {
    const int bi = kt & 1;
    __syncthreads();                    // drains prefetch into buf bi
    if (kt + 1 < 64) STAGE_OL(kt + 1, bi ^ 1);

    // ---- QK (swapped): scores for 2 m-tiles x 32 keys; K-frag is the A
    // operand so the output is C[key][q] -> P-row is lane-local.
    f32x4 sc[2][2];
    #pragma unroll
    for (int mi = 0; mi < 2; ++mi)
      #pragma unroll
      for (int nc = 0; nc < 2; ++nc) sc[mi][nc] = (f32x4){0.f,0.f,0.f,0.f};
    #pragma unroll
    for (int ks = 0; ks < 8; ++ks) {
      bf16x8 kf0 = *(const bf16x8*)&Kt[bi][sw32(c,      ks*4 + qd)];
      bf16x8 kf1 = *(const bf16x8*)&Kt[bi][sw32(16 + c, ks*4 + qd)];
      #pragma unroll
      for (int mi = 0; mi < 2; ++mi) {
        sc[mi][0] = __builtin_amdgcn_mfma_f32_16x16x32_bf16(kf0, qa[mi][ks], sc[mi][0], 0, 0, 0);
        sc[mi][1] = __builtin_amdgcn_mfma_f32_16x16x32_bf16(kf1, qa[mi][ks], sc[mi][1], 0, 0, 0);
      }
    }
    // ---- exp (unnormalized), accumulate L, pack P in-register.
    // sc[mi][nc][r] = S[key = kt*32 + 8*qd + 4*nc + r][q = 16*mi + c], so the
    // PV A-frag dword j is pk(ex[j>>1][2*(j&1)], ex[j>>1][2*(j&1)+1]).
    bf16x8 pa[2];
    #pragma unroll
    for (int mi = 0; mi < 2; ++mi) {
      float ex[2][4];
      #pragma unroll
      for (int nc = 0; nc < 2; ++nc)
        #pragma unroll
        for (int r = 0; r < 4; ++r) {
          float p = __expf(sc[mi][nc][r]);
          ex[nc][r] = p;
          Lp[mi] += p;
        }
      union { unsigned u[4]; bf16x8 v; } cv;
      asm("v_cvt_pk_bf16_f32 %0, %1, %2" : "=v"(cv.u[0]) : "v"(ex[0][0]), "v"(ex[0][1]));
      asm("v_cvt_pk_bf16_f32 %0, %1, %2" : "=v"(cv.u[1]) : "v"(ex[0][2]), "v"(ex[0][3]));
      asm("v_cvt_pk_bf16_f32 %0, %1, %2" : "=v"(cv.u[2]) : "v"(ex[1][0]), "v"(ex[1][1]));
      asm("v_cvt_pk_bf16_f32 %0, %1, %2" : "=v"(cv.u[3]) : "v"(ex[1][2]), "v"(ex[1][3]));
      pa[mi] = cv.v;
    }
    // ---- PV: each V read feeds 2 MFMA; conflict-free padded-chunk layout
    #pragma unroll
    for (int ec = 0; ec < 16; ++ec) {
      bf16x8 vf = *(const bf16x8*)&Vt[bi][ec*544 + c*32 + (qd ^ ((c >> 1) & 3))*8];
      o[0][ec] = __builtin_amdgcn_mfma_f32_16x16x32_bf16(pa[0], vf, o[0][ec], 0, 0, 0);
      o[1][ec] = __builtin_amdgcn_mfma_f32_16x16x32_bf16(pa[1], vf, o[1][ec], 0, 0, 0);
    }
  }

  // ---- epilogue per m-tile: reduce L across qd-groups, store L,
  // redistribute 1/L to the O layout (rows qd*4+r), normalize, store zcat.
  #pragma unroll
  for (int mi = 0; mi < 2; ++mi) {
    float L = Lp[mi];
    L += __shfl_xor(L, 16);
    L += __shfl_xor(L, 32);          // all lanes now hold L for q = 16*mi + c
    if (qd == 0)
      Lws[(size_t)h*N_ + b*S_ + s0 + 32*w + 16*mi + c] = L;
    float il[4];
    #pragma unroll
    for (int r = 0; r < 4; ++r)
      il[r] = 1.0f / __shfl(L, (lane & 48) | (qd*4 + r));
    #pragma unroll
    for (int ec = 0; ec < 16; ++ec)
      #pragma unroll
      for (int r = 0; r < 4; ++r)
        zcatb[(size_t)(b*S_ + s0 + 32*w + 16*mi + qd*4 + r)*HD_ + h*D_ + ec*16 + c] =
            f2bf(o[mi][ec][r] * il[r]);
  }
  #undef STAGE_OL
}

// ---------------------------------------------------------------------------
// Kernel B2+C (round-9 fat merge): blocks 0..2047 run attn_mean v11 (the
// verified 163-us dbuf structure); blocks 2048..2303 run wz_ln1 (verbatim).
// The two are data-disjoint (attn_mean: qb/kb/Lws -> out_attn; wz_ln1:
// zcatb/X/Wz -> z1b) and both depend only on attn_ol, so the wz blocks
// (dispatched last) execute concurrently with attn_mean's tail instead of
// serially after it -- hiding wz_ln1's runtime + one launch gap.
// Shared memory manually unioned: max(attn 64 KB, wz 74.2 KB) = 74.2 KB
// -> still 2 blocks/CU. Branch is block-uniform (legal w/ __syncthreads).
// grid 2304 (1-D), block 256.
// ---------------------------------------------------------------------------
#define FATSMEM (73728 + 512)
__global__ __launch_bounds__(256, 2) void attn_mean_wz_kernel(
    const unsigned short* __restrict__ qb, const unsigned short* __restrict__ kb,
    const float* __restrict__ Lws, float* __restrict__ out_attn,
    const unsigned short* __restrict__ zcatb, const unsigned short* __restrict__ Wzt,
    const float* __restrict__ bz, const float* __restrict__ X,
    const float* __restrict__ g1, const float* __restrict__ be1,
    unsigned short* __restrict__ z1b)
{
  __shared__ __align__(16) char smem[FATSMEM];
  const int tid = threadIdx.x;
  const int w = tid >> 6, lane = tid & 63;
  const int c = lane & 15, qd = lane >> 4;
  const int bid = blockIdx.x;

  if (bid < 2048) {
    // ================= attn_mean v11 (verified round-3 structure) ========
    unsigned short (*Kt)[64*32*8] = (unsigned short (*)[64*32*8])smem; // 2x32KB
    // XCD-pinned decode: group g = (b, t-block); 16 s-blocks of g share XCD.
    const int xcd = bid & 7;
    const int slot = bid >> 3;         // 0..255
    const int j = slot & 15;           // s-block index
    const int ggg = slot >> 4;         // 0..15
    const int g = ggg*8 + xcd;         // 0..127, g%8 == xcd
    const int b = g >> 5;
    const int t0 = (g & 31) * 64;
    const int s0 = j * 128;

    float am[2][4][4] = {};   // [mi][nc][r]

    #define STAGE_AM(h_, bi_)                                                  \
      {                                                                        \
        const char* kB = (const char*)(kb + (size_t)(h_)*N_*D_ + (size_t)b*S_*D_);\
        _Pragma("unroll")                                                      \
        for (int i = 0; i < 8; ++i) {                                          \
          int gq = w*8 + i;                                                    \
          int r = 2*gq + (lane >> 5);                                          \
          int su = lane & 31;                                                  \
          int u = (su & 24) | ((su & 7) ^ (r & 7));                            \
          glds16(kB + ((size_t)t0 + r)*512 + u*16, &Kt[bi_][gq*512]);          \
        }                                                                      \
      }

    STAGE_AM(0, 0);

    // Q prefetch pipeline: qa holds current head, qn next head.
    bf16x8 qa[2][8];
    #pragma unroll
    for (int mi = 0; mi < 2; ++mi) {
      const unsigned short* qrow = qb + (size_t)b*S_*D_ + (size_t)(s0 + 32*w + 16*mi + c)*D_ + qd*8;
      #pragma unroll
      for (int ks = 0; ks < 8; ++ks) qa[mi][ks] = *(const bf16x8*)(qrow + ks*32);
    }

    for (int h = 0; h < 8; ++h) {
      const int bi = h & 1;
      __syncthreads();
      if (h + 1 < 8) STAGE_AM(h + 1, bi ^ 1);

      // 1/L for current head: issue early (consumed after MFMA+exp).
      float il[2][4];
      #pragma unroll
      for (int mi = 0; mi < 2; ++mi)
        #pragma unroll
        for (int r = 0; r < 4; ++r)
          il[mi][r] = 0.125f / Lws[(size_t)h*N_ + b*S_ + s0 + 32*w + 16*mi + qd*4 + r];

      // Prefetch next head's Q frags (overlaps current head's MFMA chain).
      bf16x8 qn[2][8];
      if (h + 1 < 8) {
        const size_t basen = (size_t)(h+1)*N_*D_ + (size_t)b*S_*D_;
        #pragma unroll
        for (int mi = 0; mi < 2; ++mi) {
          const unsigned short* qrow = qb + basen + (size_t)(s0 + 32*w + 16*mi + c)*D_ + qd*8;
          #pragma unroll
          for (int ks = 0; ks < 8; ++ks) qn[mi][ks] = *(const bf16x8*)(qrow + ks*32);
        }
      }

      f32x4 sc[2][4];
      #pragma unroll
      for (int mi = 0; mi < 2; ++mi)
        #pragma unroll
        for (int nc = 0; nc < 4; ++nc) sc[mi][nc] = (f32x4){0.f,0.f,0.f,0.f};
      #pragma unroll
      for (int ks = 0; ks < 8; ++ks) {
        #pragma unroll
        for (int nc = 0; nc < 4; ++nc) {
          bf16x8 kf = *(const bf16x8*)&Kt[bi][sw32(nc*16 + c, ks*4 + qd)];
          sc[0][nc] = __builtin_amdgcn_mfma_f32_16x16x32_bf16(qa[0][ks], kf, sc[0][nc], 0, 0, 0);
          sc[1][nc] = __builtin_amdgcn_mfma_f32_16x16x32_bf16(qa[1][ks], kf, sc[1][nc], 0, 0, 0);
        }
      }
      #pragma unroll
      for (int mi = 0; mi < 2; ++mi)
        #pragma unroll
        for (int nc = 0; nc < 4; ++nc)
          #pragma unroll
          for (int r = 0; r < 4; ++r)
            am[mi][nc][r] += __expf(sc[mi][nc][r]) * il[mi][r];

      if (h + 1 < 8) {
        #pragma unroll
        for (int mi = 0; mi < 2; ++mi)
          #pragma unroll
          for (int ks = 0; ks < 8; ++ks) qa[mi][ks] = qn[mi][ks];
      }
    }
    #pragma unroll
    for (int mi = 0; mi < 2; ++mi)
      #pragma unroll
      for (int nc = 0; nc < 4; ++nc)
        #pragma unroll
        for (int r = 0; r < 4; ++r)
          out_attn[(size_t)(b*S_ + s0 + 32*w + 16*mi + qd*4 + r)*S_ + t0 + nc*16 + c] =
              am[mi][nc][r];
    #undef STAGE_AM
  } else {
    // ================= wz_ln1 (verbatim body, smem-cast arrays) ==========
    unsigned short* At  = (unsigned short*)smem;            // 8 KB
    unsigned short* Wt2 = (unsigned short*)(smem + 8192);   // 64 KB
    float (*redS)[32] = (float (*)[32])(smem + 73728);      // 256 B
    float (*redQ)[32] = (float (*)[32])(smem + 73728 + 256);// 256 B
    const int n0 = (bid - 2048) * 32;
    const int w4 = w;
    const int msub = w4 & 1, ehalf = w4 >> 1;

    f32x4 acc[8];
    #pragma unroll
    for (int nc = 0; nc < 8; ++nc) acc[nc] = (f32x4){0.f,0.f,0.f,0.f};

    for (int kc = 0; kc < 16; ++kc) {
      {
        const char* ab = (const char*)zcatb + (size_t)n0*4096 + (size_t)kc*256;
        #pragma unroll
        for (int i = 0; i < 2; ++i) {
          int g = w4*2 + i;
          int r = g*4 + (lane >> 4);
          int su = lane & 15;
          int u = (su & 8) | ((su & 7) ^ (r & 7));
          glds16(ab + (size_t)r*4096 + u*16, &At[g*512]);
        }
        const char* wb = (const char*)Wzt + (size_t)kc*256;
        #pragma unroll
        for (int i = 0; i < 16; ++i) {
          int g = w4*16 + i;
          int e = g*4 + (lane >> 4);
          int su = lane & 15;
          int u = (su & 8) | ((su & 7) ^ (e & 7));
          glds16(wb + (size_t)e*4096 + u*16, &Wt2[g*512]);
        }
      }
      __syncthreads();
      #pragma unroll
      for (int ks = 0; ks < 4; ++ks) {
        bf16x8 a = *(const bf16x8*)&At[sw16(msub*16 + c, ks*4 + qd)];
        #pragma unroll
        for (int nc = 0; nc < 8; ++nc) {
          bf16x8 bv = *(const bf16x8*)&Wt2[sw16(ehalf*128 + nc*16 + c, ks*4 + qd)];
          acc[nc] = __builtin_amdgcn_mfma_f32_16x16x32_bf16(a, bv, acc[nc], 0, 0, 0);
        }
      }
      __syncthreads();
    }

    float vals[8][4];
    float sum_[4] = {0.f,0.f,0.f,0.f}, sq_[4] = {0.f,0.f,0.f,0.f};
    #pragma unroll
    for (int nc = 0; nc < 8; ++nc) {
      int e = ehalf*128 + nc*16 + c;
      #pragma unroll
      for (int r = 0; r < 4; ++r) {
        int n = n0 + msub*16 + qd*4 + r;
        float v = acc[nc][r] + bz[e] + X[(size_t)n*D_ + e];
        vals[nc][r] = v;
        sum_[r] += v; sq_[r] += v*v;
      }
    }
    #pragma unroll
    for (int off = 1; off < 16; off <<= 1) {
      #pragma unroll
      for (int r = 0; r < 4; ++r) {
        sum_[r] += __shfl_xor(sum_[r], off);
        sq_[r]  += __shfl_xor(sq_[r],  off);
      }
    }
    if (c == 0) {
      #pragma unroll
      for (int r = 0; r < 4; ++r) {
        redS[ehalf][msub*16 + qd*4 + r] = sum_[r];
        redQ[ehalf][msub*16 + qd*4 + r] = sq_[r];
      }
    }
    __syncthreads();
    #pragma unroll
    for (int r = 0; r < 4; ++r) {
      int lr = msub*16 + qd*4 + r;
      float Sv = redS[0][lr] + redS[1][lr];
      float Qv = redQ[0][lr] + redQ[1][lr];
      float mean = Sv * (1.0f/D_);
      float var  = Qv * (1.0f/D_) - mean*mean;
      float rstd = rsqrtf(var + EPS);
      int n = n0 + lr;
      #pragma unroll
      for (int nc = 0; nc < 8; ++nc) {
        int e = ehalf*128 + nc*16 + c;
        z1b[(size_t)n*D_ + e] = f2bf((vals[nc][r] - mean)*rstd*g1[e] + be1[e]);
      }
    }
  }
}

// ---------------------------------------------------------------------------
// Kernel D1: h = relu(z1 @ W1 + b1), bf16 out. grid (128, 8), block 256.
// (unchanged)
// ---------------------------------------------------------------------------
__global__ __launch_bounds__(256) void mlp1_kernel(
    const unsigned short* __restrict__ z1b, const unsigned short* __restrict__ W1t,
    const float* __restrict__ b1, unsigned short* __restrict__ hbuf)
{
  __shared__ unsigned short At[64*32*8];     // 32 KB
  __shared__ unsigned short Bt[64*32*8];     // 32 KB
  const int tid = threadIdx.x;
  const int w4 = tid >> 6, lane = tid & 63;
  const int c = lane & 15, qd = lane >> 4;
  const int n0 = blockIdx.x * 64;
  const int f0 = blockIdx.y * 64;

  {
    const char* ag = (const char*)z1b + (size_t)n0*512;
    const char* bg = (const char*)W1t + (size_t)f0*512;
    #pragma unroll
    for (int i = 0; i < 8; ++i) {
      int g = w4*8 + i;
      int r = 2*g + (lane >> 5);
      int su = lane & 31;
      int u = (su & 24) | ((su & 7) ^ (r & 7));
      glds16(ag + (size_t)r*512 + u*16, &At[g*512]);
      glds16(bg + (size_t)r*512 + u*16, &Bt[g*512]);
    }
  }
  __syncthreads();

  f32x4 sc[4];
  #pragma unroll
  for (int nc = 0; nc < 4; ++nc) sc[nc] = (f32x4){0.f,0.f,0.f,0.f};
  #pragma unroll
  for (int ks = 0; ks < 8; ++ks) {
    bf16x8 xa = *(const bf16x8*)&At[sw32(16*w4 + c, ks*4 + qd)];
    #pragma unroll
    for (int nc = 0; nc < 4; ++nc) {
      bf16x8 bf = *(const bf16x8*)&Bt[sw32(nc*16 + c, ks*4 + qd)];
      sc[nc] = __builtin_amdgcn_mfma_f32_16x16x32_bf16(xa, bf, sc[nc], 0, 0, 0);
    }
  }
  #pragma unroll
  for (int nc = 0; nc < 4; ++nc) {
    int f = f0 + nc*16 + c;
    float bias = b1[f];
    #pragma unroll
    for (int r = 0; r < 4; ++r)
      hbuf[(size_t)(n0 + 16*w4 + qd*4 + r)*FD_ + f] = f2bf(fmaxf(sc[nc][r] + bias, 0.f));
  }
}

// ---------------------------------------------------------------------------
// Kernel D2: z_ff = h @ W2 + b2; out = LN2(z_ff + z1). grid 256, block 256.
// (unchanged)
// ---------------------------------------------------------------------------
__global__ __launch_bounds__(256) void mlp2_kernel(
    const unsigned short* __restrict__ hbuf, const unsigned short* __restrict__ W2t,
    const float* __restrict__ b2, const unsigned short* __restrict__ z1b,
    const float* __restrict__ g2, const float* __restrict__ be2,
    float* __restrict__ out)
{
  __shared__ unsigned short At[32*16*8];     // 8 KB
  __shared__ unsigned short Wt2[256*16*8];   // 64 KB
  __shared__ float redS[2][32], redQ[2][32];
  const int tid = threadIdx.x;
  const int w4 = tid >> 6, lane = tid & 63;
  const int c = lane & 15, qd = lane >> 4;
  const int n0 = blockIdx.x * 32;
  const int msub = w4 & 1, ehalf = w4 >> 1;

  f32x4 acc[8];
  #pragma unroll
  for (int nc = 0; nc < 8; ++nc) acc[nc] = (f32x4){0.f,0.f,0.f,0.f};

  for (int kc = 0; kc < 4; ++kc) {
    {
      const char* ab = (const char*)hbuf + (size_t)n0*1024 + (size_t)kc*256;
      #pragma unroll
      for (int i = 0; i < 2; ++i) {
        int g = w4*2 + i;
        int r = g*4 + (lane >> 4);
        int su = lane & 15;
        int u = (su & 8) | ((su & 7) ^ (r & 7));
        glds16(ab + (size_t)r*1024 + u*16, &At[g*512]);
      }
      const char* wb = (const char*)W2t + (size_t)kc*256;
      #pragma unroll
      for (int i = 0; i < 16; ++i) {
        int g = w4*16 + i;
        int e = g*4 + (lane >> 4);
        int su = lane & 15;
        int u = (su & 8) | ((su & 7) ^ (e & 7));
        glds16(wb + (size_t)e*1024 + u*16, &Wt2[g*512]);
      }
    }
    __syncthreads();
    #pragma unroll
    for (int ks = 0; ks < 4; ++ks) {
      bf16x8 a = *(const bf16x8*)&At[sw16(msub*16 + c, ks*4 + qd)];
      #pragma unroll
      for (int nc = 0; nc < 8; ++nc) {
        bf16x8 bv = *(const bf16x8*)&Wt2[sw16(ehalf*128 + nc*16 + c, ks*4 + qd)];
        acc[nc] = __builtin_amdgcn_mfma_f32_16x16x32_bf16(a, bv, acc[nc], 0, 0, 0);
      }
    }
    __syncthreads();
  }

  float vals[8][4];
  float sum_[4] = {0.f,0.f,0.f,0.f}, sq_[4] = {0.f,0.f,0.f,0.f};
  #pragma unroll
  for (int nc = 0; nc < 8; ++nc) {
    int e = ehalf*128 + nc*16 + c;
    #pragma unroll
    for (int r = 0; r < 4; ++r) {
      int n = n0 + msub*16 + qd*4 + r;
      float v = acc[nc][r] + b2[e] + bf2f(z1b[(size_t)n*D_ + e]);
      vals[nc][r] = v;
      sum_[r] += v; sq_[r] += v*v;
    }
  }
  #pragma unroll
  for (int off = 1; off < 16; off <<= 1) {
    #pragma unroll
    for (int r = 0; r < 4; ++r) {
      sum_[r] += __shfl_xor(sum_[r], off);
      sq_[r]  += __shfl_xor(sq_[r],  off);
    }
  }
  if (c == 0) {
    #pragma unroll
    for (int r = 0; r < 4; ++r) {
      redS[ehalf][msub*16 + qd*4 + r] = sum_[r];
      redQ[ehalf][msub*16 + qd*4 + r] = sq_[r];
    }
  }
  __syncthreads();
  #pragma unroll
  for (int r = 0; r < 4; ++r) {
    int lr = msub*16 + qd*4 + r;
    float Sv = redS[0][lr] + redS[1][lr];
    float Qv = redQ[0][lr] + redQ[1][lr];
    float mean = Sv * (1.0f/D_);
    float var  = Qv * (1.0f/D_) - mean*mean;
    float rstd = rsqrtf(var + EPS);
    int n = n0 + lr;
    #pragma unroll
    for (int nc = 0; nc < 8; ++nc) {
      int e = ehalf*128 + nc*16 + c;
      out[(size_t)n*D_ + e] = (vals[nc][r] - mean)*rstd*g2[e] + be2[e];
    }
  }
}

// ---------------------------------------------------------------------------
// ws layout: Xb | Wt | Wzt | W1t | W2t | qb kb vb vT | Lws | zcatb | z1b | hbuf
// d_out: z [N*D] then attn_mean [B*S*S].
// ---------------------------------------------------------------------------
extern "C" void kernel_launch(void* const* d_in, const int* in_sizes, int n_in,
                              void* d_out, int out_size, void* d_ws, size_t ws_size,
                              hipStream_t stream)
{
  (void)in_sizes; (void)n_in; (void)out_size; (void)ws_size;
  const float* X   = (const float*)d_in[0];
  const float* Wq  = (const float*)d_in[1];
  const float* Wk  = (const float*)d_in[2];
  const float* Wv  = (const float*)d_in[3];
  const float* Wz  = (const float*)d_in[4];
  const float* bz  = (const float*)d_in[5];
  const float* W1  = (const float*)d_in[6];
  const float* b1  = (const float*)d_in[7];
  const float* W2  = (const float*)d_in[8];
  const float* b2  = (const float*)d_in[9];
  const float* g1  = (const float*)d_in[10];
  const float* be1 = (const float*)d_in[11];
  const float* g2  = (const float*)d_in[12];
  const float* be2 = (const float*)d_in[13];

  char* p = (char*)d_ws;
  unsigned short* Xbb  = (unsigned short*)p; p += (size_t)N_*D_*2;
  unsigned short* Wtb  = (unsigned short*)p; p += (size_t)24*D_*D_*2;
  unsigned short* Wztb = (unsigned short*)p; p += (size_t)D_*HD_*2;
  unsigned short* W1tb = (unsigned short*)p; p += (size_t)FD_*D_*2;
  unsigned short* W2tb = (unsigned short*)p; p += (size_t)D_*FD_*2;
  unsigned short* qbuf = (unsigned short*)p; p += (size_t)H_*N_*D_*2;
  unsigned short* kbuf = (unsigned short*)p; p += (size_t)H_*N_*D_*2;
  unsigned short* vbuf = (unsigned short*)p; p += (size_t)H_*N_*D_*2;
  unsigned short* vTb  = (unsigned short*)p; p += (size_t)H_*N_*D_*2;
  float* Lws   = (float*)p; p += (size_t)H_*N_*4;
  unsigned short* zcatb = (unsigned short*)p; p += (size_t)N_*HD_*2;
  unsigned short* z1b   = (unsigned short*)p; p += (size_t)N_*D_*2;
  unsigned short* hbuf  = (unsigned short*)p;

  float* out_z    = (float*)d_out;
  float* out_attn = out_z + (size_t)N_*D_;

  cast_x_kernel<<<N_*D_/(256*8), 256, 0, stream>>>(X, Xbb);

  dim3 gW(4, 4, 24);
  prep_w_kernel<<<gW, 256, 0, stream>>>(Wq, Wk, Wv, Wtb);

  { dim3 g(HD_/64, D_/64);  tcast_kernel<<<g, 256, 0, stream>>>(Wz, Wztb, HD_, D_); }
  { dim3 g(D_/64, FD_/64);  tcast_kernel<<<g, 256, 0, stream>>>(W1, W1tb, D_, FD_); }
  { dim3 g(FD_/64, D_/64);  tcast_kernel<<<g, 256, 0, stream>>>(W2, W2tb, FD_, D_); }

  dim3 gA(N_/64, D_/64, 24);
  qkv_kernel<<<gA, 256, 0, stream>>>(Xbb, Wtb, qbuf, kbuf, vbuf);

  dim3 gT(S_/64, D_/64, H_*B_);
  vtrans_kernel<<<gT, 256, 0, stream>>>(vbuf, vTb);

  attn_ol_kernel<<<512, 256, 0, stream>>>(qbuf, kbuf, vTb, zcatb, Lws);

  // Fat launch: attn_mean (2048 blocks) + wz_ln1 (256 blocks), concurrent.
  attn_mean_wz_kernel<<<2304, 256, 0, stream>>>(
      qbuf, kbuf, Lws, out_attn, zcatb, Wztb, bz, X, g1, be1, z1b);

  dim3 gM1(N_/64, FD_/64);
  mlp1_kernel<<<gM1, 256, 0, stream>>>(z1b, W1tb, b1, hbuf);

  mlp2_kernel<<<N_/32, 256, 0, stream>>>(hbuf, W2tb, b2, z1b, g2, be2, out_z);
}

// Round 10
// 498.633 us; speedup vs baseline: 1.1089x; 1.0569x over previous
//
#include <hip/hip_runtime.h>
#include <cstdint>
#include <cstddef>

// Problem constants (match reference)
#define B_  4
#define S_  2048
#define D_  256
#define H_  8
#define FD_ 512              // F*D
#define N_  (B_*S_)          // 8192 rows
#define HD_ (H_*D_)          // 2048 concat dim
#define EPS 1e-5f

typedef __attribute__((ext_vector_type(8))) short bf16x8;   // 8 bf16 in 4 VGPRs
typedef __attribute__((ext_vector_type(8))) unsigned short u16x8;
typedef __attribute__((ext_vector_type(4))) float f32x4;

__device__ __forceinline__ unsigned short f2bf(float f) {
  union { float f; unsigned u; } x; x.f = f;
  unsigned u = x.u;
  return (unsigned short)((u + 0x7FFFu + ((u >> 16) & 1u)) >> 16);  // RNE
}
__device__ __forceinline__ float bf2f(unsigned short h) {
  union { unsigned u; float f; } x; x.u = ((unsigned)h) << 16; return x.f;
}

// Coalesced async global->LDS, 16 B/lane; LDS dest = wave-uniform base +
// lane*16 (m104/m108); gptr is per-lane (lets us permute the source).
__device__ __forceinline__ void glds16(const void* gptr, void* ldsptr) {
  __builtin_amdgcn_global_load_lds(
      (__attribute__((address_space(1))) void*)gptr,
      (__attribute__((address_space(3))) void*)ldsptr,
      16, 0, 0);
}

// XOR-swizzled LDS tile addressing (in shorts; unit = 16 B).
// Row r, unit u stored at (u&~7)|((u&7)^(r&7)) -> conflict-free b128 phases.
__device__ __forceinline__ int sw32(int row, int u) {      // 32 units/row (512 B)
  return (row*32 + ((u & 24) | ((u & 7) ^ (row & 7)))) * 8;
}
__device__ __forceinline__ int sw16(int row, int u) {      // 16 units/row (256 B)
  return (row*16 + ((u & 8) | ((u & 7) ^ (row & 7)))) * 8;
}

// ---------------------------------------------------------------------------
// Fat prep kernel (round-10): cast_x (blocks 0..1023) U prep_w (1024..1407)
// U tcast Wz (1408..1535) U tcast W1 (1536..1567) U tcast W2 (1568..1599).
// All five are mutually independent; merging removes 4 launch gaps.
// grid 1600, block 256.
// ---------------------------------------------------------------------------
__global__ __launch_bounds__(256) void prep_fat_kernel(
    const float* __restrict__ X, unsigned short* __restrict__ Xb,
    const float* __restrict__ Wq, const float* __restrict__ Wk,
    const float* __restrict__ Wv, unsigned short* __restrict__ Wt,
    const float* __restrict__ Wz, unsigned short* __restrict__ Wzt,
    const float* __restrict__ W1, unsigned short* __restrict__ W1t,
    const float* __restrict__ W2, unsigned short* __restrict__ W2t)
{
  __shared__ float tile[64][65];
  const int tid = threadIdx.x;
  const int bid = blockIdx.x;

  if (bid < 1024) {
    // ---- cast_x: X fp32 -> bf16 --------------------------------------
    const size_t i8 = ((size_t)bid * 256 + tid) * 8;
    float4 a = *(const float4*)&X[i8];
    float4 b = *(const float4*)&X[i8 + 4];
    u16x8 o;
    o[0]=f2bf(a.x); o[1]=f2bf(a.y); o[2]=f2bf(a.z); o[3]=f2bf(a.w);
    o[4]=f2bf(b.x); o[5]=f2bf(b.y); o[6]=f2bf(b.z); o[7]=f2bf(b.w);
    *(u16x8*)&Xb[i8] = o;
    return;
  }

  const float* src;
  unsigned short* dst_base;
  int R, C;
  float scale = 1.0f;
  int d0, e0;          // prep_w coords / tcast (r0,c0)
  bool is_prepw = false;
  int wsel = 0;

  if (bid < 1408) {
    // ---- prep_w: Wq/Wk/Wv [h][d][e] -> Wt [w][e][d], scale 0.25 for q,k
    int idx = bid - 1024;               // 0..383  (4 x 4 x 24)
    d0 = (idx & 3) * 64;
    e0 = ((idx >> 2) & 3) * 64;
    wsel = idx >> 4;                    // 0..23
    if (wsel < 8)       { src = Wq + (size_t)wsel*D_*D_;      scale = 0.25f; }
    else if (wsel < 16) { src = Wk + (size_t)(wsel-8)*D_*D_;  scale = 0.25f; }
    else                { src = Wv + (size_t)(wsel-16)*D_*D_; scale = 1.0f;  }
    R = D_; C = D_;
    dst_base = Wt;                      // handled specially below
    is_prepw = true;
  } else if (bid < 1536) {
    int idx = bid - 1408;               // 0..127  (32 x 4), R=HD_, C=D_
    d0 = (idx & 31) * 64;               // r0
    e0 = (idx >> 5) * 64;               // c0
    src = Wz; dst_base = Wzt; R = HD_; C = D_;
  } else if (bid < 1568) {
    int idx = bid - 1536;               // 0..31 (4 x 8), R=D_, C=FD_
    d0 = (idx & 3) * 64;
    e0 = (idx >> 2) * 64;
    src = W1; dst_base = W1t; R = D_; C = FD_;
  } else {
    int idx = bid - 1568;               // 0..31 (8 x 4), R=FD_, C=D_
    d0 = (idx & 7) * 64;
    e0 = (idx >> 3) * 64;
    src = W2; dst_base = W2t; R = FD_; C = D_;
  }

  // ---- shared transpose-cast body: src[R][C] tile at (d0, e0) ----------
  {
    int r = tid >> 2, c16 = (tid & 3) * 16;
    const float* s = src + (size_t)(d0 + r)*C + e0 + c16;
    #pragma unroll
    for (int u = 0; u < 4; ++u) *(float4*)&tile[r][c16 + u*4] = *(const float4*)(s + u*4);
  }
  __syncthreads();
  {
    int cr = tid >> 2, rc = (tid & 3) * 16;
    u16x8 o0, o1;
    #pragma unroll
    for (int j = 0; j < 8; ++j) {
      o0[j] = f2bf(tile[rc + j][cr] * scale);
      o1[j] = f2bf(tile[rc + 8 + j][cr] * scale);
    }
    unsigned short* d;
    if (is_prepw)
      d = dst_base + ((size_t)wsel*D_ + e0 + cr)*D_ + d0 + rc;
    else
      d = dst_base + (size_t)(e0 + cr)*R + d0 + rc;
    *(u16x8*)(d)     = o0;
    *(u16x8*)(d + 8) = o1;
  }
}

// ---------------------------------------------------------------------------
// Kernel A (round-10): QKV projections + INLINE V TRANSPOSE.
// q/k z-slices (w<16): unchanged row-major store. V slices (w>=16): after
// the MFMA loop (barrier -> Xt dead), scatter sc into a [t][e] LDS tile
// aliased onto Xt, barrier, write vT[h*4+b][e][t] coalescedly (vtrans's
// epilogue verbatim). Eliminates the vtrans kernel + 64 MB of vbuf traffic.
// grid (128, 4, 24), block 256.
// ---------------------------------------------------------------------------
__global__ __launch_bounds__(256) void qkv_kernel(
    const unsigned short* __restrict__ Xb, const unsigned short* __restrict__ Wt,
    unsigned short* __restrict__ q, unsigned short* __restrict__ k,
    unsigned short* __restrict__ vT)
{
  __shared__ unsigned short Xt[64*32*8];     // 32 KB
  __shared__ unsigned short Wtile[64*32*8];  // 32 KB
  const int tid = threadIdx.x;
  const int w4 = tid >> 6, lane = tid & 63;
  const int c = lane & 15, qd = lane >> 4;
  const int n0 = blockIdx.x * 64;
  const int e0 = blockIdx.y * 64;
  const int w  = blockIdx.z;

  {
    const char* xg = (const char*)Xb + (size_t)n0*512;
    const char* wg = (const char*)Wt + ((size_t)w*D_ + e0)*512;
    #pragma unroll
    for (int i = 0; i < 8; ++i) {
      int g = w4*8 + i;
      int r = 2*g + (lane >> 5);
      int su = lane & 31;
      int u = (su & 24) | ((su & 7) ^ (r & 7));
      glds16(xg + (size_t)r*512 + u*16, &Xt[g*512]);
      glds16(wg + (size_t)r*512 + u*16, &Wtile[g*512]);
    }
  }
  __syncthreads();

  f32x4 sc[4];
  #pragma unroll
  for (int nc = 0; nc < 4; ++nc) sc[nc] = (f32x4){0.f,0.f,0.f,0.f};
  #pragma unroll
  for (int ks = 0; ks < 8; ++ks) {
    bf16x8 xa = *(const bf16x8*)&Xt[sw32(16*w4 + c, ks*4 + qd)];
    #pragma unroll
    for (int nc = 0; nc < 4; ++nc) {
      bf16x8 bf = *(const bf16x8*)&Wtile[sw32(nc*16 + c, ks*4 + qd)];
      sc[nc] = __builtin_amdgcn_mfma_f32_16x16x32_bf16(xa, bf, sc[nc], 0, 0, 0);
    }
  }

  if (w < 16) {
    unsigned short* obase = (w < 8) ? (q + (size_t)w*N_*D_)
                                    : (k + (size_t)(w-8)*N_*D_);
    #pragma unroll
    for (int nc = 0; nc < 4; ++nc)
      #pragma unroll
      for (int r = 0; r < 4; ++r)
        obase[(size_t)(n0 + 16*w4 + qd*4 + r)*D_ + e0 + nc*16 + c] = f2bf(sc[nc][r]);
  } else {
    // ---- inline V transpose: sc[nc][r] = V[n0+16w4+qd*4+r][e0+nc*16+c]
    const int h = w - 16;
    const int b = n0 >> 11;            // n0 / S_
    const int t0 = n0 & (S_ - 1);      // n0 % S_ (block rows share one b)
    unsigned short (*tile)[72] = (unsigned short (*)[72])Xt;  // 18 KB of 32
    __syncthreads();                   // all waves done reading Xt/Wtile
    #pragma unroll
    for (int nc = 0; nc < 4; ++nc)
      #pragma unroll
      for (int r = 0; r < 4; ++r)
        tile[16*w4 + qd*4 + r][nc*16 + c] = f2bf(sc[nc][r]);
    __syncthreads();
    {
      int er = tid >> 2, tt = (tid & 3) * 16;
      u16x8 o0, o1;
      #pragma unroll
      for (int j = 0; j < 8; ++j) { o0[j] = tile[tt+j][er]; o1[j] = tile[tt+8+j][er]; }
      unsigned short* dst = vT + ((size_t)(h*4 + b)*D_ + e0 + er)*S_ + t0 + tt;
      *(u16x8*)(dst)     = o0;
      *(u16x8*)(dst + 8) = o1;
    }
  }
}

// ---------------------------------------------------------------------------
// Kernel B1 (v11, verified 163 us / FETCH 49 MB): attention O + L.
// Swapped QK, permuted K staging, in-register P via cvt_pk, XCD-pinned
// 1-D grid. LDS 66 KB -> 2 blocks/CU. grid 512 (1-D), block 256.
// ---------------------------------------------------------------------------
__global__ __launch_bounds__(256, 2) void attn_ol_kernel(
    const unsigned short* __restrict__ qb, const unsigned short* __restrict__ kb,
    const unsigned short* __restrict__ vT, unsigned short* __restrict__ zcatb,
    float* __restrict__ Lws)
{
  __shared__ unsigned short Kt[2][32*32*8];   // 2 x 16 KB, swizzled 512B rows
  __shared__ unsigned short Vt[2][16*544];    // 2 x 17408 B, padded-chunk + perm
  const int tid = threadIdx.x;
  const int w = tid >> 6, lane = tid & 63;
  const int c = lane & 15, qd = lane >> 4;
  // XCD-pinned decode: group g = (h,b) pair; all 16 s-blocks of g share XCD.
  const int wg = blockIdx.x;
  const int xcd = wg & 7;
  const int slot = wg >> 3;          // 0..63
  const int j = slot & 15;           // s-block index
  const int gg = slot >> 4;          // 0..3
  const int g = gg*8 + xcd;          // 0..31, g%8 == xcd
  const int h = g >> 2, b = g & 3;
  const int s0 = j * 128;

  const size_t qkbase = (size_t)h*N_*D_ + (size_t)b*S_*D_;

  // Q frags for both m-tiles (held in registers all kernel); used as the
  // B-operand of the swapped QK MFMA (fragment layout is role-agnostic).
  bf16x8 qa[2][8];
  #pragma unroll
  for (int mi = 0; mi < 2; ++mi) {
    const unsigned short* qrow = qb + qkbase + (size_t)(s0 + 32*w + 16*mi + c)*D_ + qd*8;
    #pragma unroll
    for (int ks = 0; ks < 8; ++ks) qa[mi][ks] = *(const bf16x8*)(qrow + ks*32);
  }

  f32x4 o[2][16];
  #pragma unroll
  for (int mi = 0; mi < 2; ++mi)
    #pragma unroll
    for (int i = 0; i < 16; ++i) o[mi][i] = (f32x4){0.f,0.f,0.f,0.f};
  float Lp[2] = {0.f, 0.f};   // per-lane partial row-sum for q = 16*mi + c

  const char* kB = (const char*)(kb + qkbase);                       // key rows: 512 B
  const char* vB = (const char*)(vT + (size_t)(h*4 + b)*D_*S_);      // e rows: 4096 B

  // K staging: physical score-row r is loaded from logical key row L(r)
  // within the tile, so the swapped-QK output keys land grouped-by-8 per qd.
  // V chunk gq: e-rows gq*16..+16, 64 B per row (32 keys), lane l carries
  // (row r = l>>2, stored pos p = l&3) -> logical t-unit q = p ^ ((r>>1)&3).
  #define STAGE_OL(kt_, bi_)                                                   \
    {                                                                          \
      _Pragma("unroll")                                                        \
      for (int i = 0; i < 4; ++i) {                                            \
        int gq = w*4 + i;                                                      \
        int r = 2*gq + (lane >> 5);                                            \
        int Lg = ((r >> 2) & 3)*8 + (r >> 4)*4 + (r & 3);                      \
        int su = lane & 31;                                                    \
        int u = (su & 24) | ((su & 7) ^ (r & 7));                              \
        glds16(kB + ((size_t)(kt_)*32 + Lg)*512 + u*16, &Kt[bi_][gq*512]);     \
      }                                                                        \
      _Pragma("unroll")                                                        \
      for (int i = 0; i < 4; ++i) {                                            \
        int gq = w*4 + i;                                                      \
        int e = gq*16 + (lane >> 2);                                           \
        int qv = (lane & 3) ^ ((lane >> 3) & 3);                               \
        glds16(vB + (size_t)e*4096 + (size_t)(kt_)*64 + qv*16, &Vt[bi_][gq*544]);\
      }                                                                        \
    }

  STAGE_OL(0, 0);

  for (int kt = 0; kt < 64; ++kt) {
    const int bi = kt & 1;
    __syncthreads();                    // drains prefetch into buf bi
    if (kt + 1 < 64) STAGE_OL(kt + 1, bi ^ 1);

    // ---- QK (swapped): scores for 2 m-tiles x 32 keys; K-frag is the A
    // operand so the output is C[key][q] -> P-row is lane-local.
    f32x4 sc[2][2];
    #pragma unroll
    for (int mi = 0; mi < 2; ++mi)
      #pragma unroll
      for (int nc = 0; nc < 2; ++nc) sc[mi][nc] = (f32x4){0.f,0.f,0.f,0.f};
    #pragma unroll
    for (int ks = 0; ks < 8; ++ks) {
      bf16x8 kf0 = *(const bf16x8*)&Kt[bi][sw32(c,      ks*4 + qd)];
      bf16x8 kf1 = *(const bf16x8*)&Kt[bi][sw32(16 + c, ks*4 + qd)];
      #pragma unroll
      for (int mi = 0; mi < 2; ++mi) {
        sc[mi][0] = __builtin_amdgcn_mfma_f32_16x16x32_bf16(kf0, qa[mi][ks], sc[mi][0], 0, 0, 0);
        sc[mi][1] = __builtin_amdgcn_mfma_f32_16x16x32_bf16(kf1, qa[mi][ks], sc[mi][1], 0, 0, 0);
      }
    }
    // ---- exp (unnormalized), accumulate L, pack P in-register.
    // sc[mi][nc][r] = S[key = kt*32 + 8*qd + 4*nc + r][q = 16*mi + c], so the
    // PV A-frag dword j is pk(ex[j>>1][2*(j&1)], ex[j>>1][2*(j&1)+1]).
    bf16x8 pa[2];
    #pragma unroll
    for (int mi = 0; mi < 2; ++mi) {
      float ex[2][4];
      #pragma unroll
      for (int nc = 0; nc < 2; ++nc)
        #pragma unroll
        for (int r = 0; r < 4; ++r) {
          float p = __expf(sc[mi][nc][r]);
          ex[nc][r] = p;
          Lp[mi] += p;
        }
      union { unsigned u[4]; bf16x8 v; } cv;
      asm("v_cvt_pk_bf16_f32 %0, %1, %2" : "=v"(cv.u[0]) : "v"(ex[0][0]), "v"(ex[0][1]));
      asm("v_cvt_pk_bf16_f32 %0, %1, %2" : "=v"(cv.u[1]) : "v"(ex[0][2]), "v"(ex[0][3]));
      asm("v_cvt_pk_bf16_f32 %0, %1, %2" : "=v"(cv.u[2]) : "v"(ex[1][0]), "v"(ex[1][1]));
      asm("v_cvt_pk_bf16_f32 %0, %1, %2" : "=v"(cv.u[3]) : "v"(ex[1][2]), "v"(ex[1][3]));
      pa[mi] = cv.v;
    }
    // ---- PV: each V read feeds 2 MFMA; conflict-free padded-chunk layout
    #pragma unroll
    for (int ec = 0; ec < 16; ++ec) {
      bf16x8 vf = *(const bf16x8*)&Vt[bi][ec*544 + c*32 + (qd ^ ((c >> 1) & 3))*8];
      o[0][ec] = __builtin_amdgcn_mfma_f32_16x16x32_bf16(pa[0], vf, o[0][ec], 0, 0, 0);
      o[1][ec] = __builtin_amdgcn_mfma_f32_16x16x32_bf16(pa[1], vf, o[1][ec], 0, 0, 0);
    }
  }

  // ---- epilogue per m-tile: reduce L across qd-groups, store L,
  // redistribute 1/L to the O layout (rows qd*4+r), normalize, store zcat.
  #pragma unroll
  for (int mi = 0; mi < 2; ++mi) {
    float L = Lp[mi];
    L += __shfl_xor(L, 16);
    L += __shfl_xor(L, 32);          // all lanes now hold L for q = 16*mi + c
    if (qd == 0)
      Lws[(size_t)h*N_ + b*S_ + s0 + 32*w + 16*mi + c] = L;
    float il[4];
    #pragma unroll
    for (int r = 0; r < 4; ++r)
      il[r] = 1.0f / __shfl(L, (lane & 48) | (qd*4 + r));
    #pragma unroll
    for (int ec = 0; ec < 16; ++ec)
      #pragma unroll
      for (int r = 0; r < 4; ++r)
        zcatb[(size_t)(b*S_ + s0 + 32*w + 16*mi + qd*4 + r)*HD_ + h*D_ + ec*16 + c] =
            f2bf(o[mi][ec][r] * il[r]);
  }
  #undef STAGE_OL
}

// ---------------------------------------------------------------------------
// Kernel B2+C (fat merge, verified 196.8 us): blocks 0..2047 attn_mean v11;
// blocks 2048..2303 wz_ln1. Data-disjoint, both depend only on attn_ol.
// Shared memory manually unioned (74.2 KB) -> 2 blocks/CU.
// grid 2304 (1-D), block 256. (unchanged from round 9)
// ---------------------------------------------------------------------------
#define FATSMEM (73728 + 512)
__global__ __launch_bounds__(256, 2) void attn_mean_wz_kernel(
    const unsigned short* __restrict__ qb, const unsigned short* __restrict__ kb,
    const float* __restrict__ Lws, float* __restrict__ out_attn,
    const unsigned short* __restrict__ zcatb, const unsigned short* __restrict__ Wzt,
    const float* __restrict__ bz, const float* __restrict__ X,
    const float* __restrict__ g1, const float* __restrict__ be1,
    unsigned short* __restrict__ z1b)
{
  __shared__ __align__(16) char smem[FATSMEM];
  const int tid = threadIdx.x;
  const int w = tid >> 6, lane = tid & 63;
  const int c = lane & 15, qd = lane >> 4;
  const int bid = blockIdx.x;

  if (bid < 2048) {
    // ================= attn_mean v11 (verified round-3 structure) ========
    unsigned short (*Kt)[64*32*8] = (unsigned short (*)[64*32*8])smem; // 2x32KB
    // XCD-pinned decode: group g = (b, t-block); 16 s-blocks of g share XCD.
    const int xcd = bid & 7;
    const int slot = bid >> 3;         // 0..255
    const int j = slot & 15;           // s-block index
    const int ggg = slot >> 4;         // 0..15
    const int g = ggg*8 + xcd;         // 0..127, g%8 == xcd
    const int b = g >> 5;
    const int t0 = (g & 31) * 64;
    const int s0 = j * 128;

    float am[2][4][4] = {};   // [mi][nc][r]

    #define STAGE_AM(h_, bi_)                                                  \
      {                                                                        \
        const char* kB = (const char*)(kb + (size_t)(h_)*N_*D_ + (size_t)b*S_*D_);\
        _Pragma("unroll")                                                      \
        for (int i = 0; i < 8; ++i) {                                          \
          int gq = w*8 + i;                                                    \
          int r = 2*gq + (lane >> 5);                                          \
          int su = lane & 31;                                                  \
          int u = (su & 24) | ((su & 7) ^ (r & 7));                            \
          glds16(kB + ((size_t)t0 + r)*512 + u*16, &Kt[bi_][gq*512]);          \
        }                                                                      \
      }

    STAGE_AM(0, 0);

    // Q prefetch pipeline: qa holds current head, qn next head.
    bf16x8 qa[2][8];
    #pragma unroll
    for (int mi = 0; mi < 2; ++mi) {
      const unsigned short* qrow = qb + (size_t)b*S_*D_ + (size_t)(s0 + 32*w + 16*mi + c)*D_ + qd*8;
      #pragma unroll
      for (int ks = 0; ks < 8; ++ks) qa[mi][ks] = *(const bf16x8*)(qrow + ks*32);
    }

    for (int h = 0; h < 8; ++h) {
      const int bi = h & 1;
      __syncthreads();
      if (h + 1 < 8) STAGE_AM(h + 1, bi ^ 1);

      // 1/L for current head: issue early (consumed after MFMA+exp).
      float il[2][4];
      #pragma unroll
      for (int mi = 0; mi < 2; ++mi)
        #pragma unroll
        for (int r = 0; r < 4; ++r)
          il[mi][r] = 0.125f / Lws[(size_t)h*N_ + b*S_ + s0 + 32*w + 16*mi + qd*4 + r];

      // Prefetch next head's Q frags (overlaps current head's MFMA chain).
      bf16x8 qn[2][8];
      if (h + 1 < 8) {
        const size_t basen = (size_t)(h+1)*N_*D_ + (size_t)b*S_*D_;
        #pragma unroll
        for (int mi = 0; mi < 2; ++mi) {
          const unsigned short* qrow = qb + basen + (size_t)(s0 + 32*w + 16*mi + c)*D_ + qd*8;
          #pragma unroll
          for (int ks = 0; ks < 8; ++ks) qn[mi][ks] = *(const bf16x8*)(qrow + ks*32);
        }
      }

      f32x4 sc[2][4];
      #pragma unroll
      for (int mi = 0; mi < 2; ++mi)
        #pragma unroll
        for (int nc = 0; nc < 4; ++nc) sc[mi][nc] = (f32x4){0.f,0.f,0.f,0.f};
      #pragma unroll
      for (int ks = 0; ks < 8; ++ks) {
        #pragma unroll
        for (int nc = 0; nc < 4; ++nc) {
          bf16x8 kf = *(const bf16x8*)&Kt[bi][sw32(nc*16 + c, ks*4 + qd)];
          sc[0][nc] = __builtin_amdgcn_mfma_f32_16x16x32_bf16(qa[0][ks], kf, sc[0][nc], 0, 0, 0);
          sc[1][nc] = __builtin_amdgcn_mfma_f32_16x16x32_bf16(qa[1][ks], kf, sc[1][nc], 0, 0, 0);
        }
      }
      #pragma unroll
      for (int mi = 0; mi < 2; ++mi)
        #pragma unroll
        for (int nc = 0; nc < 4; ++nc)
          #pragma unroll
          for (int r = 0; r < 4; ++r)
            am[mi][nc][r] += __expf(sc[mi][nc][r]) * il[mi][r];

      if (h + 1 < 8) {
        #pragma unroll
        for (int mi = 0; mi < 2; ++mi)
          #pragma unroll
          for (int ks = 0; ks < 8; ++ks) qa[mi][ks] = qn[mi][ks];
      }
    }
    #pragma unroll
    for (int mi = 0; mi < 2; ++mi)
      #pragma unroll
      for (int nc = 0; nc < 4; ++nc)
        #pragma unroll
        for (int r = 0; r < 4; ++r)
          out_attn[(size_t)(b*S_ + s0 + 32*w + 16*mi + qd*4 + r)*S_ + t0 + nc*16 + c] =
              am[mi][nc][r];
    #undef STAGE_AM
  } else {
    // ================= wz_ln1 (verbatim body, smem-cast arrays) ==========
    unsigned short* At  = (unsigned short*)smem;            // 8 KB
    unsigned short* Wt2 = (unsigned short*)(smem + 8192);   // 64 KB
    float (*redS)[32] = (float (*)[32])(smem + 73728);      // 256 B
    float (*redQ)[32] = (float (*)[32])(smem + 73728 + 256);// 256 B
    const int n0 = (bid - 2048) * 32;
    const int w4 = w;
    const int msub = w4 & 1, ehalf = w4 >> 1;

    f32x4 acc[8];
    #pragma unroll
    for (int nc = 0; nc < 8; ++nc) acc[nc] = (f32x4){0.f,0.f,0.f,0.f};

    for (int kc = 0; kc < 16; ++kc) {
      {
        const char* ab = (const char*)zcatb + (size_t)n0*4096 + (size_t)kc*256;
        #pragma unroll
        for (int i = 0; i < 2; ++i) {
          int g = w4*2 + i;
          int r = g*4 + (lane >> 4);
          int su = lane & 15;
          int u = (su & 8) | ((su & 7) ^ (r & 7));
          glds16(ab + (size_t)r*4096 + u*16, &At[g*512]);
        }
        const char* wb = (const char*)Wzt + (size_t)kc*256;
        #pragma unroll
        for (int i = 0; i < 16; ++i) {
          int g = w4*16 + i;
          int e = g*4 + (lane >> 4);
          int su = lane & 15;
          int u = (su & 8) | ((su & 7) ^ (e & 7));
          glds16(wb + (size_t)e*4096 + u*16, &Wt2[g*512]);
        }
      }
      __syncthreads();
      #pragma unroll
      for (int ks = 0; ks < 4; ++ks) {
        bf16x8 a = *(const bf16x8*)&At[sw16(msub*16 + c, ks*4 + qd)];
        #pragma unroll
        for (int nc = 0; nc < 8; ++nc) {
          bf16x8 bv = *(const bf16x8*)&Wt2[sw16(ehalf*128 + nc*16 + c, ks*4 + qd)];
          acc[nc] = __builtin_amdgcn_mfma_f32_16x16x32_bf16(a, bv, acc[nc], 0, 0, 0);
        }
      }
      __syncthreads();
    }

    float vals[8][4];
    float sum_[4] = {0.f,0.f,0.f,0.f}, sq_[4] = {0.f,0.f,0.f,0.f};
    #pragma unroll
    for (int nc = 0; nc < 8; ++nc) {
      int e = ehalf*128 + nc*16 + c;
      #pragma unroll
      for (int r = 0; r < 4; ++r) {
        int n = n0 + msub*16 + qd*4 + r;
        float v = acc[nc][r] + bz[e] + X[(size_t)n*D_ + e];
        vals[nc][r] = v;
        sum_[r] += v; sq_[r] += v*v;
      }
    }
    #pragma unroll
    for (int off = 1; off < 16; off <<= 1) {
      #pragma unroll
      for (int r = 0; r < 4; ++r) {
        sum_[r] += __shfl_xor(sum_[r], off);
        sq_[r]  += __shfl_xor(sq_[r],  off);
      }
    }
    if (c == 0) {
      #pragma unroll
      for (int r = 0; r < 4; ++r) {
        redS[ehalf][msub*16 + qd*4 + r] = sum_[r];
        redQ[ehalf][msub*16 + qd*4 + r] = sq_[r];
      }
    }
    __syncthreads();
    #pragma unroll
    for (int r = 0; r < 4; ++r) {
      int lr = msub*16 + qd*4 + r;
      float Sv = redS[0][lr] + redS[1][lr];
      float Qv = redQ[0][lr] + redQ[1][lr];
      float mean = Sv * (1.0f/D_);
      float var  = Qv * (1.0f/D_) - mean*mean;
      float rstd = rsqrtf(var + EPS);
      int n = n0 + lr;
      #pragma unroll
      for (int nc = 0; nc < 8; ++nc) {
        int e = ehalf*128 + nc*16 + c;
        z1b[(size_t)n*D_ + e] = f2bf((vals[nc][r] - mean)*rstd*g1[e] + be1[e]);
      }
    }
  }
}

// ---------------------------------------------------------------------------
// Kernel D1: h = relu(z1 @ W1 + b1), bf16 out. grid (128, 8), block 256.
// (unchanged)
// ---------------------------------------------------------------------------
__global__ __launch_bounds__(256) void mlp1_kernel(
    const unsigned short* __restrict__ z1b, const unsigned short* __restrict__ W1t,
    const float* __restrict__ b1, unsigned short* __restrict__ hbuf)
{
  __shared__ unsigned short At[64*32*8];     // 32 KB
  __shared__ unsigned short Bt[64*32*8];     // 32 KB
  const int tid = threadIdx.x;
  const int w4 = tid >> 6, lane = tid & 63;
  const int c = lane & 15, qd = lane >> 4;
  const int n0 = blockIdx.x * 64;
  const int f0 = blockIdx.y * 64;

  {
    const char* ag = (const char*)z1b + (size_t)n0*512;
    const char* bg = (const char*)W1t + (size_t)f0*512;
    #pragma unroll
    for (int i = 0; i < 8; ++i) {
      int g = w4*8 + i;
      int r = 2*g + (lane >> 5);
      int su = lane & 31;
      int u = (su & 24) | ((su & 7) ^ (r & 7));
      glds16(ag + (size_t)r*512 + u*16, &At[g*512]);
      glds16(bg + (size_t)r*512 + u*16, &Bt[g*512]);
    }
  }
  __syncthreads();

  f32x4 sc[4];
  #pragma unroll
  for (int nc = 0; nc < 4; ++nc) sc[nc] = (f32x4){0.f,0.f,0.f,0.f};
  #pragma unroll
  for (int ks = 0; ks < 8; ++ks) {
    bf16x8 xa = *(const bf16x8*)&At[sw32(16*w4 + c, ks*4 + qd)];
    #pragma unroll
    for (int nc = 0; nc < 4; ++nc) {
      bf16x8 bf = *(const bf16x8*)&Bt[sw32(nc*16 + c, ks*4 + qd)];
      sc[nc] = __builtin_amdgcn_mfma_f32_16x16x32_bf16(xa, bf, sc[nc], 0, 0, 0);
    }
  }
  #pragma unroll
  for (int nc = 0; nc < 4; ++nc) {
    int f = f0 + nc*16 + c;
    float bias = b1[f];
    #pragma unroll
    for (int r = 0; r < 4; ++r)
      hbuf[(size_t)(n0 + 16*w4 + qd*4 + r)*FD_ + f] = f2bf(fmaxf(sc[nc][r] + bias, 0.f));
  }
}

// ---------------------------------------------------------------------------
// Kernel D2: z_ff = h @ W2 + b2; out = LN2(z_ff + z1). grid 256, block 256.
// (unchanged)
// ---------------------------------------------------------------------------
__global__ __launch_bounds__(256) void mlp2_kernel(
    const unsigned short* __restrict__ hbuf, const unsigned short* __restrict__ W2t,
    const float* __restrict__ b2, const unsigned short* __restrict__ z1b,
    const float* __restrict__ g2, const float* __restrict__ be2,
    float* __restrict__ out)
{
  __shared__ unsigned short At[32*16*8];     // 8 KB
  __shared__ unsigned short Wt2[256*16*8];   // 64 KB
  __shared__ float redS[2][32], redQ[2][32];
  const int tid = threadIdx.x;
  const int w4 = tid >> 6, lane = tid & 63;
  const int c = lane & 15, qd = lane >> 4;
  const int n0 = blockIdx.x * 32;
  const int msub = w4 & 1, ehalf = w4 >> 1;

  f32x4 acc[8];
  #pragma unroll
  for (int nc = 0; nc < 8; ++nc) acc[nc] = (f32x4){0.f,0.f,0.f,0.f};

  for (int kc = 0; kc < 4; ++kc) {
    {
      const char* ab = (const char*)hbuf + (size_t)n0*1024 + (size_t)kc*256;
      #pragma unroll
      for (int i = 0; i < 2; ++i) {
        int g = w4*2 + i;
        int r = g*4 + (lane >> 4);
        int su = lane & 15;
        int u = (su & 8) | ((su & 7) ^ (r & 7));
        glds16(ab + (size_t)r*1024 + u*16, &At[g*512]);
      }
      const char* wb = (const char*)W2t + (size_t)kc*256;
      #pragma unroll
      for (int i = 0; i < 16; ++i) {
        int g = w4*16 + i;
        int e = g*4 + (lane >> 4);
        int su = lane & 15;
        int u = (su & 8) | ((su & 7) ^ (e & 7));
        glds16(wb + (size_t)e*1024 + u*16, &Wt2[g*512]);
      }
    }
    __syncthreads();
    #pragma unroll
    for (int ks = 0; ks < 4; ++ks) {
      bf16x8 a = *(const bf16x8*)&At[sw16(msub*16 + c, ks*4 + qd)];
      #pragma unroll
      for (int nc = 0; nc < 8; ++nc) {
        bf16x8 bv = *(const bf16x8*)&Wt2[sw16(ehalf*128 + nc*16 + c, ks*4 + qd)];
        acc[nc] = __builtin_amdgcn_mfma_f32_16x16x32_bf16(a, bv, acc[nc], 0, 0, 0);
      }
    }
    __syncthreads();
  }

  float vals[8][4];
  float sum_[4] = {0.f,0.f,0.f,0.f}, sq_[4] = {0.f,0.f,0.f,0.f};
  #pragma unroll
  for (int nc = 0; nc < 8; ++nc) {
    int e = ehalf*128 + nc*16 + c;
    #pragma unroll
    for (int r = 0; r < 4; ++r) {
      int n = n0 + msub*16 + qd*4 + r;
      float v = acc[nc][r] + b2[e] + bf2f(z1b[(size_t)n*D_ + e]);
      vals[nc][r] = v;
      sum_[r] += v; sq_[r] += v*v;
    }
  }
  #pragma unroll
  for (int off = 1; off < 16; off <<= 1) {
    #pragma unroll
    for (int r = 0; r < 4; ++r) {
      sum_[r] += __shfl_xor(sum_[r], off);
      sq_[r]  += __shfl_xor(sq_[r],  off);
    }
  }
  if (c == 0) {
    #pragma unroll
    for (int r = 0; r < 4; ++r) {
      redS[ehalf][msub*16 + qd*4 + r] = sum_[r];
      redQ[ehalf][msub*16 + qd*4 + r] = sq_[r];
    }
  }
  __syncthreads();
  #pragma unroll
  for (int r = 0; r < 4; ++r) {
    int lr = msub*16 + qd*4 + r;
    float Sv = redS[0][lr] + redS[1][lr];
    float Qv = redQ[0][lr] + redQ[1][lr];
    float mean = Sv * (1.0f/D_);
    float var  = Qv * (1.0f/D_) - mean*mean;
    float rstd = rsqrtf(var + EPS);
    int n = n0 + lr;
    #pragma unroll
    for (int nc = 0; nc < 8; ++nc) {
      int e = ehalf*128 + nc*16 + c;
      out[(size_t)n*D_ + e] = (vals[nc][r] - mean)*rstd*g2[e] + be2[e];
    }
  }
}

// ---------------------------------------------------------------------------
// ws layout: Xb | Wt | Wzt | W1t | W2t | qb kb vb vT | Lws | zcatb | z1b | hbuf
// (vb slot retained but unused -- vT is written directly by qkv now.)
// d_out: z [N*D] then attn_mean [B*S*S].
// ---------------------------------------------------------------------------
extern "C" void kernel_launch(void* const* d_in, const int* in_sizes, int n_in,
                              void* d_out, int out_size, void* d_ws, size_t ws_size,
                              hipStream_t stream)
{
  (void)in_sizes; (void)n_in; (void)out_size; (void)ws_size;
  const float* X   = (const float*)d_in[0];
  const float* Wq  = (const float*)d_in[1];
  const float* Wk  = (const float*)d_in[2];
  const float* Wv  = (const float*)d_in[3];
  const float* Wz  = (const float*)d_in[4];
  const float* bz  = (const float*)d_in[5];
  const float* W1  = (const float*)d_in[6];
  const float* b1  = (const float*)d_in[7];
  const float* W2  = (const float*)d_in[8];
  const float* b2  = (const float*)d_in[9];
  const float* g1  = (const float*)d_in[10];
  const float* be1 = (const float*)d_in[11];
  const float* g2  = (const float*)d_in[12];
  const float* be2 = (const float*)d_in[13];

  char* p = (char*)d_ws;
  unsigned short* Xbb  = (unsigned short*)p; p += (size_t)N_*D_*2;
  unsigned short* Wtb  = (unsigned short*)p; p += (size_t)24*D_*D_*2;
  unsigned short* Wztb = (unsigned short*)p; p += (size_t)D_*HD_*2;
  unsigned short* W1tb = (unsigned short*)p; p += (size_t)FD_*D_*2;
  unsigned short* W2tb = (unsigned short*)p; p += (size_t)D_*FD_*2;
  unsigned short* qbuf = (unsigned short*)p; p += (size_t)H_*N_*D_*2;
  unsigned short* kbuf = (unsigned short*)p; p += (size_t)H_*N_*D_*2;
  unsigned short* vbuf = (unsigned short*)p; p += (size_t)H_*N_*D_*2;  // unused
  unsigned short* vTb  = (unsigned short*)p; p += (size_t)H_*N_*D_*2;
  float* Lws   = (float*)p; p += (size_t)H_*N_*4;
  unsigned short* zcatb = (unsigned short*)p; p += (size_t)N_*HD_*2;
  unsigned short* z1b   = (unsigned short*)p; p += (size_t)N_*D_*2;
  unsigned short* hbuf  = (unsigned short*)p;
  (void)vbuf;

  float* out_z    = (float*)d_out;
  float* out_attn = out_z + (size_t)N_*D_;

  // Fat prep: cast_x U prep_w U tcast(Wz) U tcast(W1) U tcast(W2).
  prep_fat_kernel<<<1600, 256, 0, stream>>>(
      X, Xbb, Wq, Wk, Wv, Wtb, Wz, Wztb, W1, W1tb, W2, W2tb);

  dim3 gA(N_/64, D_/64, 24);
  qkv_kernel<<<gA, 256, 0, stream>>>(Xbb, Wtb, qbuf, kbuf, vTb);

  attn_ol_kernel<<<512, 256, 0, stream>>>(qbuf, kbuf, vTb, zcatb, Lws);

  // Fat launch: attn_mean (2048 blocks) + wz_ln1 (256 blocks), concurrent.
  attn_mean_wz_kernel<<<2304, 256, 0, stream>>>(
      qbuf, kbuf, Lws, out_attn, zcatb, Wztb, bz, X, g1, be1, z1b);

  dim3 gM1(N_/64, FD_/64);
  mlp1_kernel<<<gM1, 256, 0, stream>>>(z1b, W1tb, b1, hbuf);

  mlp2_kernel<<<N_/32, 256, 0, stream>>>(hbuf, W2tb, b2, z1b, g2, be2, out_z);
}